// Round 10
// baseline (156.996 us; speedup 1.0000x reference)
//
#include <hip/hip_runtime.h>
#include <cstdint>
#include <cstddef>

// NOBlock: B=4, N=2048, V=1, M=64 (8x8), C=128, rank 8, GRP=4.
//
// ALGEBRA: op is linear in x; mask only sets the divisor w (all 4 group
// members are always summed):  out = winv * (Tucker(sum_j x_j) + sum_j x_j)
// -> ONE Tucker transform per GROUP (2048 total). Memory floor ~53us.
//
// ROUND 9 FIX: stage C (z2 = core . z) previously had each thread read its
// own 2KB-strided core row -> 64 cache lines per wave load, zero coalescing,
// L1/L2 thrash (the dominant stall: VALUBusy 10%, HBM 10%). Now a tiny
// pre-kernel transposes core into d_ws as cT[k4][r] (float4 of 4 k's), so
// lane t reads cT[k4*512+t]: fully coalesced 1KB/wave-instr L2 streaming,
// 8 independent FMA chains for MLP.

__device__ __forceinline__ float dot4(const float4 a, const float4 b, float s) {
    return fmaf(a.w, b.w, fmaf(a.z, b.z, fmaf(a.y, b.y, fmaf(a.x, b.x, s))));
}

// core[r][k] (512x512) -> cT[k>>2][r] as float4 over k&3. Coalesced stores.
__global__ void transpose_core(const float* __restrict__ core,
                               float* __restrict__ coreT) {
    const int tid = blockIdx.x * 256 + threadIdx.x;   // 0..65535
    const int r = tid & 511, k4 = tid >> 9;
    ((float4*)coreT)[(size_t)k4 * 512 + r] =
        ((const float4*)core)[(size_t)r * 128 + k4];
}

template<bool TR>
__launch_bounds__(256, 3)
__global__ void noblock_kernel(const float* __restrict__ x,
                               const float* __restrict__ core,
                               const float* __restrict__ coreT,
                               const float* __restrict__ of0,
                               const float* __restrict__ of1,
                               const float* __restrict__ of2,
                               const float* __restrict__ if0,
                               const float* __restrict__ if1,
                               const float* __restrict__ if2,
                               const int* __restrict__ mask,
                               float* __restrict__ out)
{
    __shared__ float xs[64 * 132];      // 33.8 KB xsum tile (reused per group)
    __shared__ float t1[512];
    __shared__ float t2[512];
    __shared__ float zz[2 * 512];       // z per group
    __shared__ float z2[2 * 512];       // core output per group
    __shared__ float s_if2T[8 * 132];   // [F][e], padded
    __shared__ float s_if0[64], s_if1[64];
    __shared__ float s_of0T[64], s_of1T[64];   // [A][o], [B][p]
    __shared__ float s_winv[128];       // [g][m]

    const int t = threadIdx.x;
    const int blk = blockIdx.x;

    // ---- P0: stage factors + winv ----
    for (int i = t; i < 1024; i += 256) {
        const int e = i & 127, F = i >> 7;
        s_if2T[F * 132 + e] = if2[e * 8 + F];
    }
    if (t < 64) {
        s_if0[t] = if0[t];
        s_if1[t] = if1[t];
        s_of0T[t] = of0[(t & 7) * 8 + (t >> 3)];
        s_of1T[t] = of1[(t & 7) * 8 + (t >> 3)];
    }
    if (t < 128) {
        const int g = t >> 6, mm = t & 63;
        const int* mp = mask + ((size_t)(blk * 2 + g) * 4) * 64 + mm;
        int cnt = 0;
        #pragma unroll
        for (int j = 0; j < 4; ++j) cnt += (mp[j * 64] == 0) ? 1 : 0;
        s_winv[t] = cnt ? 1.0f / (float)cnt : 0.0f;
    }

    // ---- P1: load 8 tokens (256 KB contiguous), sum per group into regs ----
    // batched 8-wide temp loads for HBM MLP
    float4 acc[2][8];
    const float4* xg4 = (const float4*)(x + (size_t)blk * 8 * 8192);
    #pragma unroll
    for (int g = 0; g < 2; ++g)
        #pragma unroll
        for (int i = 0; i < 8; ++i)
            acc[g][i] = xg4[(size_t)(g * 4) * 2048 + t + 256 * i];
    #pragma unroll
    for (int j = 1; j < 4; ++j) {
        #pragma unroll
        for (int g = 0; g < 2; ++g) {
            float4 v[8];
            #pragma unroll
            for (int i = 0; i < 8; ++i)
                v[i] = xg4[(size_t)(g * 4 + j) * 2048 + t + 256 * i];
            #pragma unroll
            for (int i = 0; i < 8; ++i) {
                acc[g][i].x += v[i].x; acc[g][i].y += v[i].y;
                acc[g][i].z += v[i].z; acc[g][i].w += v[i].w;
            }
        }
    }

    // ---- per-group in-projection ----
    #pragma unroll
    for (int g = 0; g < 2; ++g) {
        // write xsum -> xs (padded rows)
        #pragma unroll
        for (int i = 0; i < 8; ++i) {
            const int f4i = t + 256 * i;
            *(float4*)&xs[(f4i >> 5) * 132 + (f4i & 31) * 4] = acc[g][i];
        }
        __syncthreads();   // (1st iter: also guards P0 staging)

        // A: t1[m*8+F] = sum_e xs[m][e] * if2T[F][e]  — all-b128 dots
        #pragma unroll
        for (int h = 0; h < 2; ++h) {
            const int id = t + 256 * h;
            const int m = id >> 3, F = id & 7;
            const float4* xr = (const float4*)(xs + m * 132);
            const float4* wr = (const float4*)(s_if2T + F * 132);
            float s0 = 0.f, s1 = 0.f;
            #pragma unroll
            for (int e4 = 0; e4 < 32; e4 += 2) {
                s0 = dot4(xr[e4],     wr[e4],     s0);
                s1 = dot4(xr[e4 + 1], wr[e4 + 1], s1);
            }
            t1[id] = s0 + s1;
        }
        __syncthreads();

        // B1: t2[E*64+a*8+F] = sum_d t1[a*64+d*8+F] * if1[d][E]
        #pragma unroll
        for (int h = 0; h < 2; ++h) {
            const int id = t + 256 * h;
            const int E = id >> 6, a = (id >> 3) & 7, F = id & 7;
            float s = 0.f;
            #pragma unroll
            for (int d0 = 0; d0 < 8; ++d0) {
                const int d = (d0 + a) & 7;           // stagger: 2-way banks
                s = fmaf(t1[a * 64 + d * 8 + F], s_if1[d * 8 + E], s);
            }
            t2[id] = s;
        }
        __syncthreads();

        // B2: zz[g][D*64+E*8+F] = sum_a t2[E*64+a*8+F] * if0[a][D]
        #pragma unroll
        for (int h = 0; h < 2; ++h) {
            const int id = t + 256 * h;
            const int D = id >> 6, E = (id >> 3) & 7, F = id & 7;
            float s = 0.f;
            #pragma unroll
            for (int a0 = 0; a0 < 8; ++a0) {
                const int a = (a0 + E) & 7;           // stagger: 2-way banks
                s = fmaf(t2[E * 64 + a * 8 + F], s_if0[a * 8 + D], s);
            }
            zz[g * 512 + id] = s;
        }
        __syncthreads();
    }

    // ---- C: z2[g][r] = sum_k core[r][k] * zz[g][k] ----
    if (TR) {
        // coalesced: cT[k4*512 + r], lane t reads consecutive float4s.
        // 8 independent accumulator chains (even/odd k4 x 2 rows x 2 groups).
        const float4* cT = (const float4*)coreT;
        const float4* z4 = (const float4*)zz;   // [g*128 + k4]
        float a00 = 0.f, a01 = 0.f, a10 = 0.f, a11 = 0.f;
        float b00 = 0.f, b01 = 0.f, b10 = 0.f, b11 = 0.f;
        #pragma unroll 2
        for (int k4 = 0; k4 < 128; k4 += 2) {
            const float4 c0  = cT[(size_t)k4 * 512 + t];
            const float4 c1  = cT[(size_t)k4 * 512 + t + 256];
            const float4 c0b = cT[(size_t)(k4 + 1) * 512 + t];
            const float4 c1b = cT[(size_t)(k4 + 1) * 512 + t + 256];
            const float4 z0  = z4[k4],     z1  = z4[128 + k4];
            const float4 z0b = z4[k4 + 1], z1b = z4[128 + k4 + 1];
            a00 = dot4(c0,  z0,  a00);  a01 = dot4(c0,  z1,  a01);
            a10 = dot4(c1,  z0,  a10);  a11 = dot4(c1,  z1,  a11);
            b00 = dot4(c0b, z0b, b00);  b01 = dot4(c0b, z1b, b01);
            b10 = dot4(c1b, z0b, b10);  b11 = dot4(c1b, z1b, b11);
        }
        z2[t]             = a00 + b00;
        z2[t + 256]       = a10 + b10;
        z2[512 + t]       = a01 + b01;
        z2[512 + t + 256] = a11 + b11;
    } else {
        // fallback: direct (strided) core rows
        const float4* cr0 = (const float4*)(core + (size_t)t * 512);
        const float4* cr1 = (const float4*)(core + (size_t)(t + 256) * 512);
        const float4* z4 = (const float4*)zz;
        float a0[2] = {0.f, 0.f}, a1[2] = {0.f, 0.f};
        for (int kk = 0; kk < 128; ++kk) {
            const float4 c0 = cr0[kk], c1 = cr1[kk];
            #pragma unroll
            for (int g = 0; g < 2; ++g) {
                const float4 zv = z4[g * 128 + kk];
                a0[g] = dot4(c0, zv, a0[g]);
                a1[g] = dot4(c1, zv, a1[g]);
            }
        }
        #pragma unroll
        for (int g = 0; g < 2; ++g) {
            z2[g * 512 + t]       = a0[g];
            z2[g * 512 + t + 256] = a1[g];
        }
    }
    __syncthreads();

    // of2 rows for this thread's 4 channels (L1-hot global)
    float4 w[4][2];
    {
        const int cc = (4 * t) & 127;
        #pragma unroll
        for (int c = 0; c < 4; ++c) {
            w[c][0] = *(const float4*)(of2 + (cc + c) * 8);
            w[c][1] = *(const float4*)(of2 + (cc + c) * 8 + 4);
        }
    }

    // ---- per-group out-projection + residual + winv + store ----
    float4* out4 = (float4*)out;
    #pragma unroll
    for (int g = 0; g < 2; ++g) {
        // D1: t1[o*64+Bq*8+Cr] = sum_A z2[g][A*64+Bq*8+Cr] * of0T[A][o]
        #pragma unroll
        for (int h = 0; h < 2; ++h) {
            const int id = t + 256 * h;
            const int o = id >> 6, Bq = (id >> 3) & 7, Cr = id & 7;
            float s = 0.f;
            #pragma unroll
            for (int A = 0; A < 8; ++A)
                s = fmaf(z2[g * 512 + A * 64 + Bq * 8 + Cr], s_of0T[A * 8 + o], s);
            t1[id] = s;
        }
        __syncthreads();

        // D2: t2[p*64+o*8+Cr] = sum_B t1[o*64+B*8+Cr] * of1T[B][p]
        #pragma unroll
        for (int h = 0; h < 2; ++h) {
            const int id = t + 256 * h;
            const int p = id >> 6, o = (id >> 3) & 7, Cr = id & 7;
            float s = 0.f;
            #pragma unroll
            for (int B0 = 0; B0 < 8; ++B0) {
                const int Bq = (B0 + o) & 7;          // stagger: 2-way banks
                s = fmaf(t1[o * 64 + Bq * 8 + Cr], s_of1T[Bq * 8 + p], s);
            }
            t2[id] = s;
        }
        __syncthreads();

        // D3: h = v . of2 + residual; * winv; store
        #pragma unroll
        for (int i = 0; i < 8; ++i) {
            const int m = (t >> 5) + 8 * i;
            const int o = m >> 3, p = m & 7;
            const float wv = s_winv[g * 64 + m];
            const int base = p * 64 + o * 8;
            const float4 v0 = *(const float4*)(t2 + base);      // broadcast
            const float4 v1 = *(const float4*)(t2 + base + 4);
            float4 r;
            r.x = dot4(v1, w[0][1], dot4(v0, w[0][0], acc[g][i].x));
            r.y = dot4(v1, w[1][1], dot4(v0, w[1][0], acc[g][i].y));
            r.z = dot4(v1, w[2][1], dot4(v0, w[2][0], acc[g][i].z));
            r.w = dot4(v1, w[3][1], dot4(v0, w[3][0], acc[g][i].w));
            r.x *= wv; r.y *= wv; r.z *= wv; r.w *= wv;
            out4[(size_t)(blk * 2 + g) * 2048 + t + 256 * i] = r;
        }
        __syncthreads();   // before next group's D1 overwrites t1
    }
}

extern "C" void kernel_launch(void* const* d_in, const int* in_sizes, int n_in,
                              void* d_out, int out_size, void* d_ws, size_t ws_size,
                              hipStream_t stream) {
    const float* x    = (const float*)d_in[0];
    const float* core = (const float*)d_in[1];
    const float* of0  = (const float*)d_in[2];
    const float* of1  = (const float*)d_in[3];
    const float* of2  = (const float*)d_in[4];
    const float* if0  = (const float*)d_in[5];
    const float* if1  = (const float*)d_in[6];
    const float* if2  = (const float*)d_in[7];
    const int* mask   = (const int*)d_in[8];
    float* out = (float*)d_out;

    const bool tr = (d_ws != nullptr) && (ws_size >= (size_t)512 * 512 * 4);
    if (tr) {
        float* coreT = (float*)d_ws;
        transpose_core<<<dim3(256), dim3(256), 0, stream>>>(core, coreT);
        noblock_kernel<true><<<dim3(1024), dim3(256), 0, stream>>>(
            x, core, coreT, of0, of1, of2, if0, if1, if2, mask, out);
    } else {
        noblock_kernel<false><<<dim3(1024), dim3(256), 0, stream>>>(
            x, core, core, of0, of1, of2, if0, if1, if2, mask, out);
    }
}

// Round 11
// 122.533 us; speedup vs baseline: 1.2813x; 1.2813x over previous
//
#include <hip/hip_runtime.h>
#include <cstdint>
#include <cstddef>

// NOBlock: B=4, N=2048, V=1, M=64 (8x8), C=128, rank 8, GRP=4.
//
// ALGEBRA: op is linear in x; mask only sets divisor w:
//   out = winv * (Tucker(sum_j x_j) + sum_j x_j)   -> one transform per GROUP.
//
// ROUND 11: split into 3 short kernels so each phase runs wide and overlaps
// internally, instead of one long barriered chain per block:
//   T:  core[512][512] -> coreT[k4][r] (coalesced stage-C reads)
//   K1: per group: xsum (+ write to d_out as residual scratch), in-proj -> zz(ws)
//   K2: 4 groups/block: z2 = coreT . zz (L2 stream, halved traffic), out-proj,
//       read xsum from d_out, +residual, *winv, overwrite d_out in place.

__device__ __forceinline__ float dot4(const float4 a, const float4 b, float s) {
    return fmaf(a.w, b.w, fmaf(a.z, b.z, fmaf(a.y, b.y, fmaf(a.x, b.x, s))));
}

// core[r][k] (512x512) -> cT[k>>2][r] as float4 over k&3. Coalesced stores.
__global__ void transpose_core(const float* __restrict__ core,
                               float* __restrict__ coreT) {
    const int tid = blockIdx.x * 256 + threadIdx.x;   // 0..65535
    const int r = tid & 511, k4 = tid >> 9;
    ((float4*)coreT)[(size_t)k4 * 512 + r] =
        ((const float4*)core)[(size_t)r * 128 + k4];
}

// ---- K1: group sum + residual scratch + in-projection -> zz ----
__launch_bounds__(256, 3)
__global__ void k1_inproj(const float* __restrict__ x,
                          const float* __restrict__ if0,
                          const float* __restrict__ if1,
                          const float* __restrict__ if2,
                          float* __restrict__ xsum_out,   // d_out as scratch
                          float* __restrict__ zz_ws)
{
    __shared__ float xs[64 * 132];      // 33.8 KB; dead after stage A
    __shared__ float t1[512];
    __shared__ float s_if2T[8 * 132];   // [F][e], padded
    __shared__ float s_if0[64], s_if1[64];
    float* t2 = xs;                     // alias (xs dead after A)

    const int t = threadIdx.x;
    const int g = blockIdx.x;           // group id 0..2047

    for (int i = t; i < 1024; i += 256) {
        const int e = i & 127, F = i >> 7;
        s_if2T[F * 132 + e] = if2[e * 8 + F];
    }
    if (t < 64) { s_if0[t] = if0[t]; s_if1[t] = if1[t]; }

    // sum 4 tokens (128 KB contiguous per block)
    const float4* xg4 = (const float4*)(x + (size_t)g * 4 * 8192);
    float4 acc[8];
    #pragma unroll
    for (int i = 0; i < 8; ++i) acc[i] = xg4[t + 256 * i];
    #pragma unroll
    for (int j = 1; j < 4; ++j) {
        float4 v[8];
        #pragma unroll
        for (int i = 0; i < 8; ++i) v[i] = xg4[(size_t)j * 2048 + t + 256 * i];
        #pragma unroll
        for (int i = 0; i < 8; ++i) {
            acc[i].x += v[i].x; acc[i].y += v[i].y;
            acc[i].z += v[i].z; acc[i].w += v[i].w;
        }
    }
    // residual scratch (coalesced) + padded LDS tile
    float4* xo = (float4*)xsum_out + (size_t)g * 2048;
    #pragma unroll
    for (int i = 0; i < 8; ++i) xo[t + 256 * i] = acc[i];
    #pragma unroll
    for (int i = 0; i < 8; ++i) {
        const int f4i = t + 256 * i;
        *(float4*)&xs[(f4i >> 5) * 132 + (f4i & 31) * 4] = acc[i];
    }
    __syncthreads();

    // A: t1[m*8+F] = sum_e xs[m][e] * if2T[F][e]
    #pragma unroll
    for (int h = 0; h < 2; ++h) {
        const int id = t + 256 * h;
        const int m = id >> 3, F = id & 7;
        const float4* xr = (const float4*)(xs + m * 132);
        const float4* wr = (const float4*)(s_if2T + F * 132);
        float s0 = 0.f, s1 = 0.f;
        #pragma unroll
        for (int e4 = 0; e4 < 32; e4 += 2) {
            s0 = dot4(xr[e4],     wr[e4],     s0);
            s1 = dot4(xr[e4 + 1], wr[e4 + 1], s1);
        }
        t1[id] = s0 + s1;
    }
    __syncthreads();

    // B1: t2[E*64+a*8+F] = sum_d t1[a*64+d*8+F] * if1[d][E]
    #pragma unroll
    for (int h = 0; h < 2; ++h) {
        const int id = t + 256 * h;
        const int E = id >> 6, a = (id >> 3) & 7, F = id & 7;
        float s = 0.f;
        #pragma unroll
        for (int d0 = 0; d0 < 8; ++d0) {
            const int d = (d0 + a) & 7;               // stagger: 2-way banks
            s = fmaf(t1[a * 64 + d * 8 + F], s_if1[d * 8 + E], s);
        }
        t2[id] = s;
    }
    __syncthreads();

    // B2: zz[g][D*64+E*8+F] = sum_a t2[E*64+a*8+F] * if0[a][D]  -> global ws
    #pragma unroll
    for (int h = 0; h < 2; ++h) {
        const int id = t + 256 * h;
        const int D = id >> 6, E = (id >> 3) & 7, F = id & 7;
        float s = 0.f;
        #pragma unroll
        for (int a0 = 0; a0 < 8; ++a0) {
            const int a = (a0 + E) & 7;               // stagger: 2-way banks
            s = fmaf(t2[E * 64 + a * 8 + F], s_if0[a * 8 + D], s);
        }
        zz_ws[(size_t)g * 512 + id] = s;              // coalesced
    }
}

// ---- K2: core contraction (4 groups/block) + out-projection + residual ----
__launch_bounds__(256, 2)
__global__ void k2_core_outproj(const float* __restrict__ coreT,
                                const float* __restrict__ zz_ws,
                                const float* __restrict__ of0,
                                const float* __restrict__ of1,
                                const float* __restrict__ of2,
                                const int* __restrict__ mask,
                                float* __restrict__ out)   // holds xsum
{
    __shared__ float zz[2048];          // dead after stage C -> t1
    __shared__ float z2[2048];          // dead after D1      -> t2
    __shared__ float s_of0T[64], s_of1T[64];   // [A][o], [B][p]
    __shared__ float s_winv[256];       // [g][m]
    float* t1 = zz;
    float* t2 = z2;

    const int t = threadIdx.x;
    const int blk = blockIdx.x;
    const size_t g0 = (size_t)blk * 4;

    // stage zz (coalesced), factors, winv
    {
        const float4* zw = (const float4*)(zz_ws + g0 * 512);
        ((float4*)zz)[t]       = zw[t];
        ((float4*)zz)[t + 256] = zw[t + 256];
    }
    if (t < 64) {
        s_of0T[t] = of0[(t & 7) * 8 + (t >> 3)];
        s_of1T[t] = of1[(t & 7) * 8 + (t >> 3)];
    }
    {
        const int g = t >> 6, m = t & 63;
        const int* mp = mask + (g0 + g) * 4 * 64 + m;
        int cnt = 0;
        #pragma unroll
        for (int j = 0; j < 4; ++j) cnt += (mp[j * 64] == 0) ? 1 : 0;
        s_winv[t] = cnt ? 1.0f / (float)cnt : 0.0f;
    }
    __syncthreads();

    // stage C: z2[g][r] = sum_k coreT[k][r] * zz[g][k], coalesced L2 stream,
    // 16 independent FMA chains (2 rows x 4 groups x even/odd k4)
    {
        const float4* cT = (const float4*)coreT;
        const float4* z4 = (const float4*)zz;
        float c0a[4] = {0,0,0,0}, c1a[4] = {0,0,0,0};
        float c0b[4] = {0,0,0,0}, c1b[4] = {0,0,0,0};
        for (int k4 = 0; k4 < 128; k4 += 2) {
            const float4 ca0 = cT[(size_t)k4 * 512 + t];
            const float4 ca1 = cT[(size_t)k4 * 512 + t + 256];
            const float4 cb0 = cT[(size_t)(k4 + 1) * 512 + t];
            const float4 cb1 = cT[(size_t)(k4 + 1) * 512 + t + 256];
            #pragma unroll
            for (int g = 0; g < 4; ++g) {
                const float4 za = z4[g * 128 + k4];       // LDS broadcast
                const float4 zb = z4[g * 128 + k4 + 1];
                c0a[g] = dot4(ca0, za, c0a[g]);
                c1a[g] = dot4(ca1, za, c1a[g]);
                c0b[g] = dot4(cb0, zb, c0b[g]);
                c1b[g] = dot4(cb1, zb, c1b[g]);
            }
        }
        #pragma unroll
        for (int g = 0; g < 4; ++g) {
            z2[g * 512 + t]       = c0a[g] + c0b[g];
            z2[g * 512 + t + 256] = c1a[g] + c1b[g];
        }
    }
    __syncthreads();   // zz dead from here

    // D1 (batched 4 groups): t1[g][o*64+Bq*8+Cr] = sum_A z2[g][A*64+Bq*8+Cr]*of0T[A][o]
    #pragma unroll
    for (int h = 0; h < 8; ++h) {
        const int id2 = t + 256 * h;
        const int g = id2 >> 9, rem = id2 & 511;
        const int o = rem >> 6, Bq = (rem >> 3) & 7, Cr = rem & 7;
        float s = 0.f;
        #pragma unroll
        for (int A = 0; A < 8; ++A)
            s = fmaf(z2[g * 512 + A * 64 + Bq * 8 + Cr], s_of0T[A * 8 + o], s);
        t1[id2] = s;
    }
    __syncthreads();   // z2 dead from here

    // D2 (batched): t2[g][p*64+o*8+Cr] = sum_B t1[g][o*64+B*8+Cr]*of1T[B][p]
    #pragma unroll
    for (int h = 0; h < 8; ++h) {
        const int id2 = t + 256 * h;
        const int g = id2 >> 9, rem = id2 & 511;
        const int p = rem >> 6, o = (rem >> 3) & 7, Cr = rem & 7;
        float s = 0.f;
        #pragma unroll
        for (int B0 = 0; B0 < 8; ++B0) {
            const int Bq = (B0 + o) & 7;              // stagger: 2-way banks
            s = fmaf(t1[g * 512 + o * 64 + Bq * 8 + Cr], s_of1T[Bq * 8 + p], s);
        }
        t2[id2] = s;
    }
    __syncthreads();

    // D3: per group: read xsum (d_out), h = v.of2 + xsum, *winv, store in place
    float4 w[4][2];
    {
        const int cc = (4 * t) & 127;
        #pragma unroll
        for (int c = 0; c < 4; ++c) {
            w[c][0] = *(const float4*)(of2 + (cc + c) * 8);
            w[c][1] = *(const float4*)(of2 + (cc + c) * 8 + 4);
        }
    }
    float4* out4 = (float4*)out;
    #pragma unroll
    for (int g = 0; g < 4; ++g) {
        const size_t obase = (g0 + g) * 2048;
        float4 xv[8];
        #pragma unroll
        for (int i = 0; i < 8; ++i) xv[i] = out4[obase + t + 256 * i];
        #pragma unroll
        for (int i = 0; i < 8; ++i) {
            const int m = (t >> 5) + 8 * i;
            const int o = m >> 3, p = m & 7;
            const float wv = s_winv[g * 64 + m];
            const int base = g * 512 + p * 64 + o * 8;
            const float4 v0 = *(const float4*)(t2 + base);    // broadcast
            const float4 v1 = *(const float4*)(t2 + base + 4);
            float4 r;
            r.x = dot4(v1, w[0][1], dot4(v0, w[0][0], xv[i].x));
            r.y = dot4(v1, w[1][1], dot4(v0, w[1][0], xv[i].y));
            r.z = dot4(v1, w[2][1], dot4(v0, w[2][0], xv[i].z));
            r.w = dot4(v1, w[3][1], dot4(v0, w[3][0], xv[i].w));
            r.x *= wv; r.y *= wv; r.z *= wv; r.w *= wv;
            out4[obase + t + 256 * i] = r;
        }
    }
}

// ================= fallback: round-10 single kernel =================
template<bool TR>
__launch_bounds__(256, 3)
__global__ void noblock_kernel(const float* __restrict__ x,
                               const float* __restrict__ core,
                               const float* __restrict__ coreT,
                               const float* __restrict__ of0,
                               const float* __restrict__ of1,
                               const float* __restrict__ of2,
                               const float* __restrict__ if0,
                               const float* __restrict__ if1,
                               const float* __restrict__ if2,
                               const int* __restrict__ mask,
                               float* __restrict__ out)
{
    __shared__ float xs[64 * 132];
    __shared__ float t1[512];
    __shared__ float t2[512];
    __shared__ float zz[2 * 512];
    __shared__ float z2[2 * 512];
    __shared__ float s_if2T[8 * 132];
    __shared__ float s_if0[64], s_if1[64];
    __shared__ float s_of0T[64], s_of1T[64];
    __shared__ float s_winv[128];

    const int t = threadIdx.x;
    const int blk = blockIdx.x;

    for (int i = t; i < 1024; i += 256) {
        const int e = i & 127, F = i >> 7;
        s_if2T[F * 132 + e] = if2[e * 8 + F];
    }
    if (t < 64) {
        s_if0[t] = if0[t];
        s_if1[t] = if1[t];
        s_of0T[t] = of0[(t & 7) * 8 + (t >> 3)];
        s_of1T[t] = of1[(t & 7) * 8 + (t >> 3)];
    }
    if (t < 128) {
        const int g = t >> 6, mm = t & 63;
        const int* mp = mask + ((size_t)(blk * 2 + g) * 4) * 64 + mm;
        int cnt = 0;
        #pragma unroll
        for (int j = 0; j < 4; ++j) cnt += (mp[j * 64] == 0) ? 1 : 0;
        s_winv[t] = cnt ? 1.0f / (float)cnt : 0.0f;
    }

    float4 acc[2][8];
    const float4* xg4 = (const float4*)(x + (size_t)blk * 8 * 8192);
    #pragma unroll
    for (int g = 0; g < 2; ++g)
        #pragma unroll
        for (int i = 0; i < 8; ++i)
            acc[g][i] = xg4[(size_t)(g * 4) * 2048 + t + 256 * i];
    #pragma unroll
    for (int j = 1; j < 4; ++j) {
        #pragma unroll
        for (int g = 0; g < 2; ++g) {
            float4 v[8];
            #pragma unroll
            for (int i = 0; i < 8; ++i)
                v[i] = xg4[(size_t)(g * 4 + j) * 2048 + t + 256 * i];
            #pragma unroll
            for (int i = 0; i < 8; ++i) {
                acc[g][i].x += v[i].x; acc[g][i].y += v[i].y;
                acc[g][i].z += v[i].z; acc[g][i].w += v[i].w;
            }
        }
    }

    #pragma unroll
    for (int g = 0; g < 2; ++g) {
        #pragma unroll
        for (int i = 0; i < 8; ++i) {
            const int f4i = t + 256 * i;
            *(float4*)&xs[(f4i >> 5) * 132 + (f4i & 31) * 4] = acc[g][i];
        }
        __syncthreads();
        #pragma unroll
        for (int h = 0; h < 2; ++h) {
            const int id = t + 256 * h;
            const int m = id >> 3, F = id & 7;
            const float4* xr = (const float4*)(xs + m * 132);
            const float4* wr = (const float4*)(s_if2T + F * 132);
            float s0 = 0.f, s1 = 0.f;
            #pragma unroll
            for (int e4 = 0; e4 < 32; e4 += 2) {
                s0 = dot4(xr[e4],     wr[e4],     s0);
                s1 = dot4(xr[e4 + 1], wr[e4 + 1], s1);
            }
            t1[id] = s0 + s1;
        }
        __syncthreads();
        #pragma unroll
        for (int h = 0; h < 2; ++h) {
            const int id = t + 256 * h;
            const int E = id >> 6, a = (id >> 3) & 7, F = id & 7;
            float s = 0.f;
            #pragma unroll
            for (int d0 = 0; d0 < 8; ++d0) {
                const int d = (d0 + a) & 7;
                s = fmaf(t1[a * 64 + d * 8 + F], s_if1[d * 8 + E], s);
            }
            t2[id] = s;
        }
        __syncthreads();
        #pragma unroll
        for (int h = 0; h < 2; ++h) {
            const int id = t + 256 * h;
            const int D = id >> 6, E = (id >> 3) & 7, F = id & 7;
            float s = 0.f;
            #pragma unroll
            for (int a0 = 0; a0 < 8; ++a0) {
                const int a = (a0 + E) & 7;
                s = fmaf(t2[E * 64 + a * 8 + F], s_if0[a * 8 + D], s);
            }
            zz[g * 512 + id] = s;
        }
        __syncthreads();
    }

    if (TR) {
        const float4* cT = (const float4*)coreT;
        const float4* z4 = (const float4*)zz;
        float a00 = 0.f, a01 = 0.f, a10 = 0.f, a11 = 0.f;
        float b00 = 0.f, b01 = 0.f, b10 = 0.f, b11 = 0.f;
        #pragma unroll 2
        for (int k4 = 0; k4 < 128; k4 += 2) {
            const float4 c0  = cT[(size_t)k4 * 512 + t];
            const float4 c1  = cT[(size_t)k4 * 512 + t + 256];
            const float4 c0b = cT[(size_t)(k4 + 1) * 512 + t];
            const float4 c1b = cT[(size_t)(k4 + 1) * 512 + t + 256];
            const float4 z0  = z4[k4],     z1  = z4[128 + k4];
            const float4 z0b = z4[k4 + 1], z1b = z4[128 + k4 + 1];
            a00 = dot4(c0,  z0,  a00);  a01 = dot4(c0,  z1,  a01);
            a10 = dot4(c1,  z0,  a10);  a11 = dot4(c1,  z1,  a11);
            b00 = dot4(c0b, z0b, b00);  b01 = dot4(c0b, z1b, b01);
            b10 = dot4(c1b, z0b, b10);  b11 = dot4(c1b, z1b, b11);
        }
        z2[t]             = a00 + b00;
        z2[t + 256]       = a10 + b10;
        z2[512 + t]       = a01 + b01;
        z2[512 + t + 256] = a11 + b11;
    } else {
        const float4* cr0 = (const float4*)(core + (size_t)t * 512);
        const float4* cr1 = (const float4*)(core + (size_t)(t + 256) * 512);
        const float4* z4 = (const float4*)zz;
        float a0[2] = {0.f, 0.f}, a1[2] = {0.f, 0.f};
        for (int kk = 0; kk < 128; ++kk) {
            const float4 c0 = cr0[kk], c1 = cr1[kk];
            #pragma unroll
            for (int g = 0; g < 2; ++g) {
                const float4 zv = z4[g * 128 + kk];
                a0[g] = dot4(c0, zv, a0[g]);
                a1[g] = dot4(c1, zv, a1[g]);
            }
        }
        #pragma unroll
        for (int g = 0; g < 2; ++g) {
            z2[g * 512 + t]       = a0[g];
            z2[g * 512 + t + 256] = a1[g];
        }
    }
    __syncthreads();

    float4 w[4][2];
    {
        const int cc = (4 * t) & 127;
        #pragma unroll
        for (int c = 0; c < 4; ++c) {
            w[c][0] = *(const float4*)(of2 + (cc + c) * 8);
            w[c][1] = *(const float4*)(of2 + (cc + c) * 8 + 4);
        }
    }

    float4* out4 = (float4*)out;
    #pragma unroll
    for (int g = 0; g < 2; ++g) {
        #pragma unroll
        for (int h = 0; h < 2; ++h) {
            const int id = t + 256 * h;
            const int o = id >> 6, Bq = (id >> 3) & 7, Cr = id & 7;
            float s = 0.f;
            #pragma unroll
            for (int A = 0; A < 8; ++A)
                s = fmaf(z2[g * 512 + A * 64 + Bq * 8 + Cr], s_of0T[A * 8 + o], s);
            t1[id] = s;
        }
        __syncthreads();
        #pragma unroll
        for (int h = 0; h < 2; ++h) {
            const int id = t + 256 * h;
            const int p = id >> 6, o = (id >> 3) & 7, Cr = id & 7;
            float s = 0.f;
            #pragma unroll
            for (int B0 = 0; B0 < 8; ++B0) {
                const int Bq = (B0 + o) & 7;
                s = fmaf(t1[o * 64 + Bq * 8 + Cr], s_of1T[Bq * 8 + p], s);
            }
            t2[id] = s;
        }
        __syncthreads();
        #pragma unroll
        for (int i = 0; i < 8; ++i) {
            const int m = (t >> 5) + 8 * i;
            const int o = m >> 3, p = m & 7;
            const float wv = s_winv[g * 64 + m];
            const int base = p * 64 + o * 8;
            const float4 v0 = *(const float4*)(t2 + base);
            const float4 v1 = *(const float4*)(t2 + base + 4);
            float4 r;
            r.x = dot4(v1, w[0][1], dot4(v0, w[0][0], acc[g][i].x));
            r.y = dot4(v1, w[1][1], dot4(v0, w[1][0], acc[g][i].y));
            r.z = dot4(v1, w[2][1], dot4(v0, w[2][0], acc[g][i].z));
            r.w = dot4(v1, w[3][1], dot4(v0, w[3][0], acc[g][i].w));
            r.x *= wv; r.y *= wv; r.z *= wv; r.w *= wv;
            out4[(size_t)(blk * 2 + g) * 2048 + t + 256 * i] = r;
        }
        __syncthreads();
    }
}

extern "C" void kernel_launch(void* const* d_in, const int* in_sizes, int n_in,
                              void* d_out, int out_size, void* d_ws, size_t ws_size,
                              hipStream_t stream) {
    const float* x    = (const float*)d_in[0];
    const float* core = (const float*)d_in[1];
    const float* of0  = (const float*)d_in[2];
    const float* of1  = (const float*)d_in[3];
    const float* of2  = (const float*)d_in[4];
    const float* if0  = (const float*)d_in[5];
    const float* if1  = (const float*)d_in[6];
    const float* if2  = (const float*)d_in[7];
    const int* mask   = (const int*)d_in[8];
    float* out = (float*)d_out;

    const size_t CORE_T_BYTES = (size_t)512 * 512 * 4;            // 1 MB
    const size_t ZZ_BYTES     = (size_t)2048 * 512 * 4;           // 4 MB

    if (d_ws && ws_size >= CORE_T_BYTES + ZZ_BYTES) {
        float* coreT = (float*)d_ws;
        float* zz_ws = (float*)((char*)d_ws + CORE_T_BYTES);
        transpose_core<<<dim3(256), dim3(256), 0, stream>>>(core, coreT);
        k1_inproj<<<dim3(2048), dim3(256), 0, stream>>>(
            x, if0, if1, if2, out, zz_ws);
        k2_core_outproj<<<dim3(512), dim3(256), 0, stream>>>(
            coreT, zz_ws, of0, of1, of2, mask, out);
    } else if (d_ws && ws_size >= CORE_T_BYTES) {
        float* coreT = (float*)d_ws;
        transpose_core<<<dim3(256), dim3(256), 0, stream>>>(core, coreT);
        noblock_kernel<true><<<dim3(1024), dim3(256), 0, stream>>>(
            x, core, coreT, of0, of1, of2, if0, if1, if2, mask, out);
    } else {
        noblock_kernel<false><<<dim3(1024), dim3(256), 0, stream>>>(
            x, core, core, of0, of1, of2, if0, if1, if2, mask, out);
    }
}

// Round 12
// 116.818 us; speedup vs baseline: 1.3439x; 1.0489x over previous
//
#include <hip/hip_runtime.h>
#include <cstdint>
#include <cstddef>

// NOBlock: B=4, N=2048, V=1, M=64 (8x8), C=128, rank 8, GRP=4.
//
// ALGEBRA: op is linear in x; mask only sets divisor w:
//   out = winv * (Tucker(sum_j x_j) + sum_j x_j)   -> one transform per GROUP.
//
// ROUND 12:
//   K1 (2112 blocks): first 64 blocks transpose core->coreT (hidden under the
//       x stream); remaining 2048 blocks: per group xsum (-> d_out as residual
//       scratch) + in-projection -> zz(ws). t1/t2 alias the dead xs tile:
//       LDS 38.5 KB -> 4 blocks/CU.
//   K2 (512 blocks x 512 thr): 4 groups/block: z2 = coreT . zz (coalesced L2
//       stream, 1 row/thread, 8 FMA chains), out-proj, +xsum, *winv, in-place.

__device__ __forceinline__ float dot4(const float4 a, const float4 b, float s) {
    return fmaf(a.w, b.w, fmaf(a.z, b.z, fmaf(a.y, b.y, fmaf(a.x, b.x, s))));
}

// ---- K1: [64 transpose blocks] + [2048 group blocks] ----
__launch_bounds__(256, 4)
__global__ void k1_inproj(const float* __restrict__ x,
                          const float* __restrict__ core,
                          float* __restrict__ coreT,
                          const float* __restrict__ if0,
                          const float* __restrict__ if1,
                          const float* __restrict__ if2,
                          float* __restrict__ xsum_out,   // d_out as scratch
                          float* __restrict__ zz_ws)
{
    __shared__ float xs[64 * 132];      // 33.8 KB; t1/t2 alias after stage A
    __shared__ float s_if2T[8 * 132];   // [F][e], padded
    __shared__ float s_if0[64], s_if1[64];
    float* t1 = xs;                     // xs dead after stage-A reads
    float* t2 = xs + 512;

    const int t = threadIdx.x;
    const int blk = blockIdx.x;

    // -- transpose blocks: core[r][k] -> coreT[k4][r] (float4 over k&3) --
    if (blk < 64) {
        const int tid = blk * 256 + t;            // 0..16383
        const float4* c4 = (const float4*)core;
        float4* cT4 = (float4*)coreT;
        #pragma unroll
        for (int q = 0; q < 4; ++q) {
            const int idx = tid + 16384 * q;      // 0..65535
            const int r = idx & 511, k4 = idx >> 9;
            cT4[(size_t)k4 * 512 + r] = c4[(size_t)r * 128 + k4];
        }
        return;
    }
    const int g = blk - 64;             // group id 0..2047

    for (int i = t; i < 1024; i += 256) {
        const int e = i & 127, F = i >> 7;
        s_if2T[F * 132 + e] = if2[e * 8 + F];
    }
    if (t < 64) { s_if0[t] = if0[t]; s_if1[t] = if1[t]; }

    // sum 4 tokens (128 KB contiguous per block)
    const float4* xg4 = (const float4*)(x + (size_t)g * 4 * 8192);
    float4 acc[8];
    #pragma unroll
    for (int i = 0; i < 8; ++i) acc[i] = xg4[t + 256 * i];
    #pragma unroll
    for (int j = 1; j < 4; ++j) {
        float4 v[8];
        #pragma unroll
        for (int i = 0; i < 8; ++i) v[i] = xg4[(size_t)j * 2048 + t + 256 * i];
        #pragma unroll
        for (int i = 0; i < 8; ++i) {
            acc[i].x += v[i].x; acc[i].y += v[i].y;
            acc[i].z += v[i].z; acc[i].w += v[i].w;
        }
    }
    // residual scratch (coalesced) + padded LDS tile
    float4* xo = (float4*)xsum_out + (size_t)g * 2048;
    #pragma unroll
    for (int i = 0; i < 8; ++i) xo[t + 256 * i] = acc[i];
    #pragma unroll
    for (int i = 0; i < 8; ++i) {
        const int f4i = t + 256 * i;
        *(float4*)&xs[(f4i >> 5) * 132 + (f4i & 31) * 4] = acc[i];
    }
    __syncthreads();

    // A: r(id) = sum_e xs[m][e] * if2T[F][e], staged via regs (t1 aliases xs)
    float r0, r1;
    #pragma unroll
    for (int h = 0; h < 2; ++h) {
        const int id = t + 256 * h;
        const int m = id >> 3, F = id & 7;
        const float4* xr = (const float4*)(xs + m * 132);
        const float4* wr = (const float4*)(s_if2T + F * 132);
        float s0 = 0.f, s1 = 0.f;
        #pragma unroll
        for (int e4 = 0; e4 < 32; e4 += 2) {
            s0 = dot4(xr[e4],     wr[e4],     s0);
            s1 = dot4(xr[e4 + 1], wr[e4 + 1], s1);
        }
        if (h == 0) r0 = s0 + s1; else r1 = s0 + s1;
    }
    __syncthreads();   // all stage-A reads of xs complete
    t1[t] = r0;
    t1[t + 256] = r1;
    __syncthreads();   // t1 ready

    // B1: t2[E*64+a*8+F] = sum_d t1[a*64+d*8+F] * if1[d][E]
    #pragma unroll
    for (int h = 0; h < 2; ++h) {
        const int id = t + 256 * h;
        const int E = id >> 6, a = (id >> 3) & 7, F = id & 7;
        float s = 0.f;
        #pragma unroll
        for (int d0 = 0; d0 < 8; ++d0) {
            const int d = (d0 + a) & 7;               // stagger: 2-way banks
            s = fmaf(t1[a * 64 + d * 8 + F], s_if1[d * 8 + E], s);
        }
        t2[id] = s;
    }
    __syncthreads();   // t2 ready

    // B2: zz[g][D*64+E*8+F] = sum_a t2[E*64+a*8+F] * if0[a][D]  -> global ws
    #pragma unroll
    for (int h = 0; h < 2; ++h) {
        const int id = t + 256 * h;
        const int D = id >> 6, E = (id >> 3) & 7, F = id & 7;
        float s = 0.f;
        #pragma unroll
        for (int a0 = 0; a0 < 8; ++a0) {
            const int a = (a0 + E) & 7;               // stagger: 2-way banks
            s = fmaf(t2[E * 64 + a * 8 + F], s_if0[a * 8 + D], s);
        }
        zz_ws[(size_t)g * 512 + id] = s;              // coalesced
    }
}

// ---- K2: core contraction (4 groups/block, 512 thr) + out-proj + residual ----
__launch_bounds__(512, 2)
__global__ void k2_core_outproj(const float* __restrict__ coreT,
                                const float* __restrict__ zz_ws,
                                const float* __restrict__ of0,
                                const float* __restrict__ of1,
                                const float* __restrict__ of2,
                                const int* __restrict__ mask,
                                float* __restrict__ out)   // holds xsum
{
    __shared__ float zz[2048];          // dead after stage C -> t1
    __shared__ float z2[2048];          // dead after D1      -> t2
    __shared__ float s_of0T[64], s_of1T[64];   // [A][o], [B][p]
    __shared__ float s_winv[256];       // [g][m]
    float* t1 = zz;
    float* t2 = z2;

    const int t = threadIdx.x;          // 0..511
    const size_t g0 = (size_t)blockIdx.x * 4;

    // stage zz (coalesced: 1 float4/thread), factors, winv
    ((float4*)zz)[t] = ((const float4*)(zz_ws + g0 * 512))[t];
    if (t < 64) {
        s_of0T[t] = of0[(t & 7) * 8 + (t >> 3)];
        s_of1T[t] = of1[(t & 7) * 8 + (t >> 3)];
    }
    if (t < 256) {
        const int g = t >> 6, m = t & 63;
        const int* mp = mask + (g0 + g) * 4 * 64 + m;
        int cnt = 0;
        #pragma unroll
        for (int j = 0; j < 4; ++j) cnt += (mp[j * 64] == 0) ? 1 : 0;
        s_winv[t] = cnt ? 1.0f / (float)cnt : 0.0f;
    }
    __syncthreads();

    // stage C: z2[g][r] = sum_k coreT[k][r] * zz[g][k]; 1 row/thread,
    // coalesced L2 stream, 8 independent FMA chains (4 groups x even/odd k4)
    {
        const float4* cT = (const float4*)coreT;
        const float4* z4 = (const float4*)zz;
        float a0[4] = {0, 0, 0, 0}, a1[4] = {0, 0, 0, 0};
        for (int k4 = 0; k4 < 128; k4 += 2) {
            const float4 c0 = cT[(size_t)k4 * 512 + t];
            const float4 c1 = cT[(size_t)(k4 + 1) * 512 + t];
            #pragma unroll
            for (int g = 0; g < 4; ++g) {
                a0[g] = dot4(c0, z4[g * 128 + k4],     a0[g]);   // LDS broadcast
                a1[g] = dot4(c1, z4[g * 128 + k4 + 1], a1[g]);
            }
        }
        #pragma unroll
        for (int g = 0; g < 4; ++g) z2[g * 512 + t] = a0[g] + a1[g];
    }
    __syncthreads();   // zz dead from here (all stage-C reads done)

    // D1 (batched): t1[g][o*64+Bq*8+Cr] = sum_A z2[g][A*64+Bq*8+Cr]*of0T[A][o]
    #pragma unroll
    for (int h = 0; h < 4; ++h) {
        const int id2 = t + 512 * h;
        const int g = id2 >> 9, rem = id2 & 511;
        const int o = rem >> 6, Bq = (rem >> 3) & 7, Cr = rem & 7;
        float s = 0.f;
        #pragma unroll
        for (int A = 0; A < 8; ++A)
            s = fmaf(z2[g * 512 + A * 64 + Bq * 8 + Cr], s_of0T[A * 8 + o], s);
        t1[id2] = s;
    }
    __syncthreads();   // z2 dead from here

    // D2 (batched): t2[g][p*64+o*8+Cr] = sum_B t1[g][o*64+B*8+Cr]*of1T[B][p]
    #pragma unroll
    for (int h = 0; h < 4; ++h) {
        const int id2 = t + 512 * h;
        const int g = id2 >> 9, rem = id2 & 511;
        const int p = rem >> 6, o = (rem >> 3) & 7, Cr = rem & 7;
        float s = 0.f;
        #pragma unroll
        for (int B0 = 0; B0 < 8; ++B0) {
            const int Bq = (B0 + o) & 7;              // stagger: 2-way banks
            s = fmaf(t1[g * 512 + o * 64 + Bq * 8 + Cr], s_of1T[Bq * 8 + p], s);
        }
        t2[id2] = s;
    }
    __syncthreads();

    // D3: per group: read xsum (d_out), h = v.of2 + xsum, *winv, store in place
    float4 w[4][2];
    {
        const int cc = (4 * t) & 127;
        #pragma unroll
        for (int c = 0; c < 4; ++c) {
            w[c][0] = *(const float4*)(of2 + (cc + c) * 8);
            w[c][1] = *(const float4*)(of2 + (cc + c) * 8 + 4);
        }
    }
    float4* out4 = (float4*)out;
    #pragma unroll
    for (int g = 0; g < 4; ++g) {
        const size_t obase = (g0 + g) * 2048;
        float4 xv[4];
        #pragma unroll
        for (int i = 0; i < 4; ++i) xv[i] = out4[obase + t + 512 * i];
        #pragma unroll
        for (int i = 0; i < 4; ++i) {
            const int m = (t >> 5) + 16 * i;
            const int o = m >> 3, p = m & 7;
            const float wv = s_winv[g * 64 + m];
            const int base = g * 512 + p * 64 + o * 8;
            const float4 v0 = *(const float4*)(t2 + base);    // broadcast
            const float4 v1 = *(const float4*)(t2 + base + 4);
            float4 r;
            r.x = dot4(v1, w[0][1], dot4(v0, w[0][0], xv[i].x));
            r.y = dot4(v1, w[1][1], dot4(v0, w[1][0], xv[i].y));
            r.z = dot4(v1, w[2][1], dot4(v0, w[2][0], xv[i].z));
            r.w = dot4(v1, w[3][1], dot4(v0, w[3][0], xv[i].w));
            r.x *= wv; r.y *= wv; r.z *= wv; r.w *= wv;
            out4[obase + t + 512 * i] = r;
        }
    }
}

// ================= fallback (no ws): single fused kernel =================
__launch_bounds__(256, 3)
__global__ void noblock_fused(const float* __restrict__ x,
                              const float* __restrict__ core,
                              const float* __restrict__ of0,
                              const float* __restrict__ of1,
                              const float* __restrict__ of2,
                              const float* __restrict__ if0,
                              const float* __restrict__ if1,
                              const float* __restrict__ if2,
                              const int* __restrict__ mask,
                              float* __restrict__ out)
{
    __shared__ float xs[64 * 132];
    __shared__ float t1[512];
    __shared__ float t2[512];
    __shared__ float zz[2 * 512];
    __shared__ float z2[2 * 512];
    __shared__ float s_if2T[8 * 132];
    __shared__ float s_if0[64], s_if1[64];
    __shared__ float s_of0T[64], s_of1T[64];
    __shared__ float s_winv[128];

    const int t = threadIdx.x;
    const int blk = blockIdx.x;

    for (int i = t; i < 1024; i += 256) {
        const int e = i & 127, F = i >> 7;
        s_if2T[F * 132 + e] = if2[e * 8 + F];
    }
    if (t < 64) {
        s_if0[t] = if0[t];
        s_if1[t] = if1[t];
        s_of0T[t] = of0[(t & 7) * 8 + (t >> 3)];
        s_of1T[t] = of1[(t & 7) * 8 + (t >> 3)];
    }
    if (t < 128) {
        const int g = t >> 6, mm = t & 63;
        const int* mp = mask + ((size_t)(blk * 2 + g) * 4) * 64 + mm;
        int cnt = 0;
        #pragma unroll
        for (int j = 0; j < 4; ++j) cnt += (mp[j * 64] == 0) ? 1 : 0;
        s_winv[t] = cnt ? 1.0f / (float)cnt : 0.0f;
    }

    float4 acc[2][8];
    const float4* xg4 = (const float4*)(x + (size_t)blk * 8 * 8192);
    #pragma unroll
    for (int g = 0; g < 2; ++g)
        #pragma unroll
        for (int i = 0; i < 8; ++i)
            acc[g][i] = xg4[(size_t)(g * 4) * 2048 + t + 256 * i];
    #pragma unroll
    for (int j = 1; j < 4; ++j) {
        #pragma unroll
        for (int g = 0; g < 2; ++g) {
            float4 v[8];
            #pragma unroll
            for (int i = 0; i < 8; ++i)
                v[i] = xg4[(size_t)(g * 4 + j) * 2048 + t + 256 * i];
            #pragma unroll
            for (int i = 0; i < 8; ++i) {
                acc[g][i].x += v[i].x; acc[g][i].y += v[i].y;
                acc[g][i].z += v[i].z; acc[g][i].w += v[i].w;
            }
        }
    }

    #pragma unroll
    for (int g = 0; g < 2; ++g) {
        #pragma unroll
        for (int i = 0; i < 8; ++i) {
            const int f4i = t + 256 * i;
            *(float4*)&xs[(f4i >> 5) * 132 + (f4i & 31) * 4] = acc[g][i];
        }
        __syncthreads();
        #pragma unroll
        for (int h = 0; h < 2; ++h) {
            const int id = t + 256 * h;
            const int m = id >> 3, F = id & 7;
            const float4* xr = (const float4*)(xs + m * 132);
            const float4* wr = (const float4*)(s_if2T + F * 132);
            float s0 = 0.f, s1 = 0.f;
            #pragma unroll
            for (int e4 = 0; e4 < 32; e4 += 2) {
                s0 = dot4(xr[e4],     wr[e4],     s0);
                s1 = dot4(xr[e4 + 1], wr[e4 + 1], s1);
            }
            t1[id] = s0 + s1;
        }
        __syncthreads();
        #pragma unroll
        for (int h = 0; h < 2; ++h) {
            const int id = t + 256 * h;
            const int E = id >> 6, a = (id >> 3) & 7, F = id & 7;
            float s = 0.f;
            #pragma unroll
            for (int d0 = 0; d0 < 8; ++d0) {
                const int d = (d0 + a) & 7;
                s = fmaf(t1[a * 64 + d * 8 + F], s_if1[d * 8 + E], s);
            }
            t2[id] = s;
        }
        __syncthreads();
        #pragma unroll
        for (int h = 0; h < 2; ++h) {
            const int id = t + 256 * h;
            const int D = id >> 6, E = (id >> 3) & 7, F = id & 7;
            float s = 0.f;
            #pragma unroll
            for (int a0 = 0; a0 < 8; ++a0) {
                const int a = (a0 + E) & 7;
                s = fmaf(t2[E * 64 + a * 8 + F], s_if0[a * 8 + D], s);
            }
            zz[g * 512 + id] = s;
        }
        __syncthreads();
    }

    {
        const float4* cr0 = (const float4*)(core + (size_t)t * 512);
        const float4* cr1 = (const float4*)(core + (size_t)(t + 256) * 512);
        const float4* z4 = (const float4*)zz;
        float a0[2] = {0.f, 0.f}, a1[2] = {0.f, 0.f};
        for (int kk = 0; kk < 128; ++kk) {
            const float4 c0 = cr0[kk], c1 = cr1[kk];
            #pragma unroll
            for (int g = 0; g < 2; ++g) {
                const float4 zv = z4[g * 128 + kk];
                a0[g] = dot4(c0, zv, a0[g]);
                a1[g] = dot4(c1, zv, a1[g]);
            }
        }
        #pragma unroll
        for (int g = 0; g < 2; ++g) {
            z2[g * 512 + t]       = a0[g];
            z2[g * 512 + t + 256] = a1[g];
        }
    }
    __syncthreads();

    float4 w[4][2];
    {
        const int cc = (4 * t) & 127;
        #pragma unroll
        for (int c = 0; c < 4; ++c) {
            w[c][0] = *(const float4*)(of2 + (cc + c) * 8);
            w[c][1] = *(const float4*)(of2 + (cc + c) * 8 + 4);
        }
    }

    float4* out4 = (float4*)out;
    #pragma unroll
    for (int g = 0; g < 2; ++g) {
        #pragma unroll
        for (int h = 0; h < 2; ++h) {
            const int id = t + 256 * h;
            const int o = id >> 6, Bq = (id >> 3) & 7, Cr = id & 7;
            float s = 0.f;
            #pragma unroll
            for (int A = 0; A < 8; ++A)
                s = fmaf(z2[g * 512 + A * 64 + Bq * 8 + Cr], s_of0T[A * 8 + o], s);
            t1[id] = s;
        }
        __syncthreads();
        #pragma unroll
        for (int h = 0; h < 2; ++h) {
            const int id = t + 256 * h;
            const int p = id >> 6, o = (id >> 3) & 7, Cr = id & 7;
            float s = 0.f;
            #pragma unroll
            for (int B0 = 0; B0 < 8; ++B0) {
                const int Bq = (B0 + o) & 7;
                s = fmaf(t1[o * 64 + Bq * 8 + Cr], s_of1T[Bq * 8 + p], s);
            }
            t2[id] = s;
        }
        __syncthreads();
        #pragma unroll
        for (int i = 0; i < 8; ++i) {
            const int m = (t >> 5) + 8 * i;
            const int o = m >> 3, p = m & 7;
            const float wv = s_winv[g * 64 + m];
            const int base = p * 64 + o * 8;
            const float4 v0 = *(const float4*)(t2 + base);
            const float4 v1 = *(const float4*)(t2 + base + 4);
            float4 r;
            r.x = dot4(v1, w[0][1], dot4(v0, w[0][0], acc[g][i].x));
            r.y = dot4(v1, w[1][1], dot4(v0, w[1][0], acc[g][i].y));
            r.z = dot4(v1, w[2][1], dot4(v0, w[2][0], acc[g][i].z));
            r.w = dot4(v1, w[3][1], dot4(v0, w[3][0], acc[g][i].w));
            r.x *= wv; r.y *= wv; r.z *= wv; r.w *= wv;
            out4[(size_t)(blk * 2 + g) * 2048 + t + 256 * i] = r;
        }
        __syncthreads();
    }
}

extern "C" void kernel_launch(void* const* d_in, const int* in_sizes, int n_in,
                              void* d_out, int out_size, void* d_ws, size_t ws_size,
                              hipStream_t stream) {
    const float* x    = (const float*)d_in[0];
    const float* core = (const float*)d_in[1];
    const float* of0  = (const float*)d_in[2];
    const float* of1  = (const float*)d_in[3];
    const float* of2  = (const float*)d_in[4];
    const float* if0  = (const float*)d_in[5];
    const float* if1  = (const float*)d_in[6];
    const float* if2  = (const float*)d_in[7];
    const int* mask   = (const int*)d_in[8];
    float* out = (float*)d_out;

    const size_t CORE_T_BYTES = (size_t)512 * 512 * 4;            // 1 MB
    const size_t ZZ_BYTES     = (size_t)2048 * 512 * 4;           // 4 MB

    if (d_ws && ws_size >= CORE_T_BYTES + ZZ_BYTES) {
        float* coreT = (float*)d_ws;
        float* zz_ws = (float*)((char*)d_ws + CORE_T_BYTES);
        k1_inproj<<<dim3(2112), dim3(256), 0, stream>>>(
            x, core, coreT, if0, if1, if2, out, zz_ws);
        k2_core_outproj<<<dim3(512), dim3(512), 0, stream>>>(
            coreT, zz_ws, of0, of1, of2, mask, out);
    } else {
        noblock_fused<<<dim3(1024), dim3(256), 0, stream>>>(
            x, core, of0, of1, of2, if0, if1, if2, mask, out);
    }
}

// Round 13
// 111.813 us; speedup vs baseline: 1.4041x; 1.0448x over previous
//
#include <hip/hip_runtime.h>
#include <cstdint>
#include <cstddef>

// NOBlock: B=4, N=2048, V=1, M=64 (8x8), C=128, rank 8, GRP=4.
//
// ALGEBRA: op is linear in x; mask only sets divisor w:
//   out = winv * (Tucker(sum_j x_j) + sum_j x_j)   -> one transform per GROUP.
//
// ROUND 13: xsum residual scratch stored as packed bf16 in ws (33.5 MB vs
// 67 MB fp32 in d_out): -67 MB HBM round-trip. |xsum|<~11 -> bf16 abs err
// ~0.02, well under the 0.225 threshold. d_out is now write-once (K2).
//   K1 (2112 blocks): 64 transpose blocks (core->coreT, hidden under the x
//       stream); 2048 group blocks: xsum -> bf16 ws + in-projection -> zz(ws).
//   K2 (512 blocks x 512 thr): 4 groups/block: z2 = coreT . zz (coalesced L2
//       stream), out-proj, + bf16 xsum residual, *winv, write d_out.

__device__ __forceinline__ float dot4(const float4 a, const float4 b, float s) {
    return fmaf(a.w, b.w, fmaf(a.z, b.z, fmaf(a.y, b.y, fmaf(a.x, b.x, s))));
}

__device__ __forceinline__ unsigned f2bf_pk(float lo, float hi) {
    // round-to-nearest-even bf16 pair packed into one uint
    unsigned ul = __float_as_uint(lo), uh = __float_as_uint(hi);
    ul += 0x7FFFu + ((ul >> 16) & 1u);
    uh += 0x7FFFu + ((uh >> 16) & 1u);
    return (ul >> 16) | (uh & 0xFFFF0000u);
}

// ---- K1: [64 transpose blocks] + [2048 group blocks] ----
__launch_bounds__(256, 4)
__global__ void k1_inproj(const float* __restrict__ x,
                          const float* __restrict__ core,
                          float* __restrict__ coreT,
                          const float* __restrict__ if0,
                          const float* __restrict__ if1,
                          const float* __restrict__ if2,
                          unsigned* __restrict__ xsum_bf,   // ws: bf16 residual
                          float* __restrict__ zz_ws)
{
    __shared__ float xs[64 * 132];      // 33.8 KB; t1/t2 alias after stage A
    __shared__ float s_if2T[8 * 132];   // [F][e], padded
    __shared__ float s_if0[64], s_if1[64];
    float* t1 = xs;                     // xs dead after stage-A reads
    float* t2 = xs + 512;

    const int t = threadIdx.x;
    const int blk = blockIdx.x;

    // -- transpose blocks: core[r][k] -> coreT[k4][r] (float4 over k&3) --
    if (blk < 64) {
        const int tid = blk * 256 + t;            // 0..16383
        const float4* c4 = (const float4*)core;
        float4* cT4 = (float4*)coreT;
        #pragma unroll
        for (int q = 0; q < 4; ++q) {
            const int idx = tid + 16384 * q;      // 0..65535
            const int r = idx & 511, k4 = idx >> 9;
            cT4[(size_t)k4 * 512 + r] = c4[(size_t)r * 128 + k4];
        }
        return;
    }
    const int g = blk - 64;             // group id 0..2047

    for (int i = t; i < 1024; i += 256) {
        const int e = i & 127, F = i >> 7;
        s_if2T[F * 132 + e] = if2[e * 8 + F];
    }
    if (t < 64) { s_if0[t] = if0[t]; s_if1[t] = if1[t]; }

    // sum 4 tokens (128 KB contiguous per block)
    const float4* xg4 = (const float4*)(x + (size_t)g * 4 * 8192);
    float4 acc[8];
    #pragma unroll
    for (int i = 0; i < 8; ++i) acc[i] = xg4[t + 256 * i];
    #pragma unroll
    for (int j = 1; j < 4; ++j) {
        float4 v[8];
        #pragma unroll
        for (int i = 0; i < 8; ++i) v[i] = xg4[(size_t)j * 2048 + t + 256 * i];
        #pragma unroll
        for (int i = 0; i < 8; ++i) {
            acc[i].x += v[i].x; acc[i].y += v[i].y;
            acc[i].z += v[i].z; acc[i].w += v[i].w;
        }
    }
    // residual scratch as packed bf16 (coalesced uint2 = 4 values / thread / i)
    uint2* xo = (uint2*)xsum_bf + (size_t)g * 2048;
    #pragma unroll
    for (int i = 0; i < 8; ++i) {
        uint2 pk;
        pk.x = f2bf_pk(acc[i].x, acc[i].y);
        pk.y = f2bf_pk(acc[i].z, acc[i].w);
        xo[t + 256 * i] = pk;
    }
    // padded LDS tile
    #pragma unroll
    for (int i = 0; i < 8; ++i) {
        const int f4i = t + 256 * i;
        *(float4*)&xs[(f4i >> 5) * 132 + (f4i & 31) * 4] = acc[i];
    }
    __syncthreads();

    // A: r(id) = sum_e xs[m][e] * if2T[F][e], staged via regs (t1 aliases xs)
    float r0, r1;
    #pragma unroll
    for (int h = 0; h < 2; ++h) {
        const int id = t + 256 * h;
        const int m = id >> 3, F = id & 7;
        const float4* xr = (const float4*)(xs + m * 132);
        const float4* wr = (const float4*)(s_if2T + F * 132);
        float s0 = 0.f, s1 = 0.f;
        #pragma unroll
        for (int e4 = 0; e4 < 32; e4 += 2) {
            s0 = dot4(xr[e4],     wr[e4],     s0);
            s1 = dot4(xr[e4 + 1], wr[e4 + 1], s1);
        }
        if (h == 0) r0 = s0 + s1; else r1 = s0 + s1;
    }
    __syncthreads();   // all stage-A reads of xs complete
    t1[t] = r0;
    t1[t + 256] = r1;
    __syncthreads();   // t1 ready

    // B1: t2[E*64+a*8+F] = sum_d t1[a*64+d*8+F] * if1[d][E]
    #pragma unroll
    for (int h = 0; h < 2; ++h) {
        const int id = t + 256 * h;
        const int E = id >> 6, a = (id >> 3) & 7, F = id & 7;
        float s = 0.f;
        #pragma unroll
        for (int d0 = 0; d0 < 8; ++d0) {
            const int d = (d0 + a) & 7;               // stagger: 2-way banks
            s = fmaf(t1[a * 64 + d * 8 + F], s_if1[d * 8 + E], s);
        }
        t2[id] = s;
    }
    __syncthreads();   // t2 ready

    // B2: zz[g][D*64+E*8+F] = sum_a t2[E*64+a*8+F] * if0[a][D]  -> global ws
    #pragma unroll
    for (int h = 0; h < 2; ++h) {
        const int id = t + 256 * h;
        const int D = id >> 6, E = (id >> 3) & 7, F = id & 7;
        float s = 0.f;
        #pragma unroll
        for (int a0 = 0; a0 < 8; ++a0) {
            const int a = (a0 + E) & 7;               // stagger: 2-way banks
            s = fmaf(t2[E * 64 + a * 8 + F], s_if0[a * 8 + D], s);
        }
        zz_ws[(size_t)g * 512 + id] = s;              // coalesced
    }
}

// ---- K2: core contraction (4 groups/block, 512 thr) + out-proj + residual ----
__launch_bounds__(512, 2)
__global__ void k2_core_outproj(const float* __restrict__ coreT,
                                const float* __restrict__ zz_ws,
                                const unsigned* __restrict__ xsum_bf,
                                const float* __restrict__ of0,
                                const float* __restrict__ of1,
                                const float* __restrict__ of2,
                                const int* __restrict__ mask,
                                float* __restrict__ out)
{
    __shared__ float zz[2048];          // dead after stage C -> t1
    __shared__ float z2[2048];          // dead after D1      -> t2
    __shared__ float s_of0T[64], s_of1T[64];   // [A][o], [B][p]
    __shared__ float s_winv[256];       // [g][m]
    float* t1 = zz;
    float* t2 = z2;

    const int t = threadIdx.x;          // 0..511
    const size_t g0 = (size_t)blockIdx.x * 4;

    // stage zz (coalesced: 1 float4/thread), factors, winv
    ((float4*)zz)[t] = ((const float4*)(zz_ws + g0 * 512))[t];
    if (t < 64) {
        s_of0T[t] = of0[(t & 7) * 8 + (t >> 3)];
        s_of1T[t] = of1[(t & 7) * 8 + (t >> 3)];
    }
    if (t < 256) {
        const int g = t >> 6, m = t & 63;
        const int* mp = mask + (g0 + g) * 4 * 64 + m;
        int cnt = 0;
        #pragma unroll
        for (int j = 0; j < 4; ++j) cnt += (mp[j * 64] == 0) ? 1 : 0;
        s_winv[t] = cnt ? 1.0f / (float)cnt : 0.0f;
    }
    __syncthreads();

    // stage C: z2[g][r] = sum_k coreT[k][r] * zz[g][k]; 1 row/thread,
    // coalesced L2 stream, 8 independent FMA chains (4 groups x even/odd k4)
    {
        const float4* cT = (const float4*)coreT;
        const float4* z4 = (const float4*)zz;
        float a0[4] = {0, 0, 0, 0}, a1[4] = {0, 0, 0, 0};
        for (int k4 = 0; k4 < 128; k4 += 2) {
            const float4 c0 = cT[(size_t)k4 * 512 + t];
            const float4 c1 = cT[(size_t)(k4 + 1) * 512 + t];
            #pragma unroll
            for (int g = 0; g < 4; ++g) {
                a0[g] = dot4(c0, z4[g * 128 + k4],     a0[g]);   // LDS broadcast
                a1[g] = dot4(c1, z4[g * 128 + k4 + 1], a1[g]);
            }
        }
        #pragma unroll
        for (int g = 0; g < 4; ++g) z2[g * 512 + t] = a0[g] + a1[g];
    }
    __syncthreads();   // zz dead from here (all stage-C reads done)

    // D1 (batched): t1[g][o*64+Bq*8+Cr] = sum_A z2[g][A*64+Bq*8+Cr]*of0T[A][o]
    #pragma unroll
    for (int h = 0; h < 4; ++h) {
        const int id2 = t + 512 * h;
        const int g = id2 >> 9, rem = id2 & 511;
        const int o = rem >> 6, Bq = (rem >> 3) & 7, Cr = rem & 7;
        float s = 0.f;
        #pragma unroll
        for (int A = 0; A < 8; ++A)
            s = fmaf(z2[g * 512 + A * 64 + Bq * 8 + Cr], s_of0T[A * 8 + o], s);
        t1[id2] = s;
    }
    __syncthreads();   // z2 dead from here

    // D2 (batched): t2[g][p*64+o*8+Cr] = sum_B t1[g][o*64+B*8+Cr]*of1T[B][p]
    #pragma unroll
    for (int h = 0; h < 4; ++h) {
        const int id2 = t + 512 * h;
        const int g = id2 >> 9, rem = id2 & 511;
        const int p = rem >> 6, o = (rem >> 3) & 7, Cr = rem & 7;
        float s = 0.f;
        #pragma unroll
        for (int B0 = 0; B0 < 8; ++B0) {
            const int Bq = (B0 + o) & 7;              // stagger: 2-way banks
            s = fmaf(t1[g * 512 + o * 64 + Bq * 8 + Cr], s_of1T[Bq * 8 + p], s);
        }
        t2[id2] = s;
    }
    __syncthreads();

    // D3: per group: h = v.of2 + bf16(xsum), *winv, write d_out (write-once)
    float4 w[4][2];
    {
        const int cc = (4 * t) & 127;
        #pragma unroll
        for (int c = 0; c < 4; ++c) {
            w[c][0] = *(const float4*)(of2 + (cc + c) * 8);
            w[c][1] = *(const float4*)(of2 + (cc + c) * 8 + 4);
        }
    }
    float4* out4 = (float4*)out;
    #pragma unroll
    for (int g = 0; g < 4; ++g) {
        const size_t obase = (g0 + g) * 2048;
        const uint2* xb = (const uint2*)xsum_bf + obase;
        uint2 xp[4];
        #pragma unroll
        for (int i = 0; i < 4; ++i) xp[i] = xb[t + 512 * i];
        #pragma unroll
        for (int i = 0; i < 4; ++i) {
            const int m = (t >> 5) + 16 * i;
            const int o = m >> 3, p = m & 7;
            const float wv = s_winv[g * 64 + m];
            const int base = g * 512 + p * 64 + o * 8;
            const float4 v0 = *(const float4*)(t2 + base);    // broadcast
            const float4 v1 = *(const float4*)(t2 + base + 4);
            // unpack bf16 residual (hi half of fp32)
            const float rx = __uint_as_float(xp[i].x << 16);
            const float ry = __uint_as_float(xp[i].x & 0xFFFF0000u);
            const float rz = __uint_as_float(xp[i].y << 16);
            const float rw = __uint_as_float(xp[i].y & 0xFFFF0000u);
            float4 r;
            r.x = dot4(v1, w[0][1], dot4(v0, w[0][0], rx));
            r.y = dot4(v1, w[1][1], dot4(v0, w[1][0], ry));
            r.z = dot4(v1, w[2][1], dot4(v0, w[2][0], rz));
            r.w = dot4(v1, w[3][1], dot4(v0, w[3][0], rw));
            r.x *= wv; r.y *= wv; r.z *= wv; r.w *= wv;
            out4[obase + t + 512 * i] = r;
        }
    }
}

// ================= fallback (no ws): single fused kernel =================
__launch_bounds__(256, 3)
__global__ void noblock_fused(const float* __restrict__ x,
                              const float* __restrict__ core,
                              const float* __restrict__ of0,
                              const float* __restrict__ of1,
                              const float* __restrict__ of2,
                              const float* __restrict__ if0,
                              const float* __restrict__ if1,
                              const float* __restrict__ if2,
                              const int* __restrict__ mask,
                              float* __restrict__ out)
{
    __shared__ float xs[64 * 132];
    __shared__ float t1[512];
    __shared__ float t2[512];
    __shared__ float zz[2 * 512];
    __shared__ float z2[2 * 512];
    __shared__ float s_if2T[8 * 132];
    __shared__ float s_if0[64], s_if1[64];
    __shared__ float s_of0T[64], s_of1T[64];
    __shared__ float s_winv[128];

    const int t = threadIdx.x;
    const int blk = blockIdx.x;

    for (int i = t; i < 1024; i += 256) {
        const int e = i & 127, F = i >> 7;
        s_if2T[F * 132 + e] = if2[e * 8 + F];
    }
    if (t < 64) {
        s_if0[t] = if0[t];
        s_if1[t] = if1[t];
        s_of0T[t] = of0[(t & 7) * 8 + (t >> 3)];
        s_of1T[t] = of1[(t & 7) * 8 + (t >> 3)];
    }
    if (t < 128) {
        const int g = t >> 6, mm = t & 63;
        const int* mp = mask + ((size_t)(blk * 2 + g) * 4) * 64 + mm;
        int cnt = 0;
        #pragma unroll
        for (int j = 0; j < 4; ++j) cnt += (mp[j * 64] == 0) ? 1 : 0;
        s_winv[t] = cnt ? 1.0f / (float)cnt : 0.0f;
    }

    float4 acc[2][8];
    const float4* xg4 = (const float4*)(x + (size_t)blk * 8 * 8192);
    #pragma unroll
    for (int g = 0; g < 2; ++g)
        #pragma unroll
        for (int i = 0; i < 8; ++i)
            acc[g][i] = xg4[(size_t)(g * 4) * 2048 + t + 256 * i];
    #pragma unroll
    for (int j = 1; j < 4; ++j) {
        #pragma unroll
        for (int g = 0; g < 2; ++g) {
            float4 v[8];
            #pragma unroll
            for (int i = 0; i < 8; ++i)
                v[i] = xg4[(size_t)(g * 4 + j) * 2048 + t + 256 * i];
            #pragma unroll
            for (int i = 0; i < 8; ++i) {
                acc[g][i].x += v[i].x; acc[g][i].y += v[i].y;
                acc[g][i].z += v[i].z; acc[g][i].w += v[i].w;
            }
        }
    }

    #pragma unroll
    for (int g = 0; g < 2; ++g) {
        #pragma unroll
        for (int i = 0; i < 8; ++i) {
            const int f4i = t + 256 * i;
            *(float4*)&xs[(f4i >> 5) * 132 + (f4i & 31) * 4] = acc[g][i];
        }
        __syncthreads();
        #pragma unroll
        for (int h = 0; h < 2; ++h) {
            const int id = t + 256 * h;
            const int m = id >> 3, F = id & 7;
            const float4* xr = (const float4*)(xs + m * 132);
            const float4* wr = (const float4*)(s_if2T + F * 132);
            float s0 = 0.f, s1 = 0.f;
            #pragma unroll
            for (int e4 = 0; e4 < 32; e4 += 2) {
                s0 = dot4(xr[e4],     wr[e4],     s0);
                s1 = dot4(xr[e4 + 1], wr[e4 + 1], s1);
            }
            t1[id] = s0 + s1;
        }
        __syncthreads();
        #pragma unroll
        for (int h = 0; h < 2; ++h) {
            const int id = t + 256 * h;
            const int E = id >> 6, a = (id >> 3) & 7, F = id & 7;
            float s = 0.f;
            #pragma unroll
            for (int d0 = 0; d0 < 8; ++d0) {
                const int d = (d0 + a) & 7;
                s = fmaf(t1[a * 64 + d * 8 + F], s_if1[d * 8 + E], s);
            }
            t2[id] = s;
        }
        __syncthreads();
        #pragma unroll
        for (int h = 0; h < 2; ++h) {
            const int id = t + 256 * h;
            const int D = id >> 6, E = (id >> 3) & 7, F = id & 7;
            float s = 0.f;
            #pragma unroll
            for (int a0 = 0; a0 < 8; ++a0) {
                const int a = (a0 + E) & 7;
                s = fmaf(t2[E * 64 + a * 8 + F], s_if0[a * 8 + D], s);
            }
            zz[g * 512 + id] = s;
        }
        __syncthreads();
    }

    {
        const float4* cr0 = (const float4*)(core + (size_t)t * 512);
        const float4* cr1 = (const float4*)(core + (size_t)(t + 256) * 512);
        const float4* z4 = (const float4*)zz;
        float a0[2] = {0.f, 0.f}, a1[2] = {0.f, 0.f};
        for (int kk = 0; kk < 128; ++kk) {
            const float4 c0 = cr0[kk], c1 = cr1[kk];
            #pragma unroll
            for (int g = 0; g < 2; ++g) {
                const float4 zv = z4[g * 128 + kk];
                a0[g] = dot4(c0, zv, a0[g]);
                a1[g] = dot4(c1, zv, a1[g]);
            }
        }
        #pragma unroll
        for (int g = 0; g < 2; ++g) {
            z2[g * 512 + t]       = a0[g];
            z2[g * 512 + t + 256] = a1[g];
        }
    }
    __syncthreads();

    float4 w[4][2];
    {
        const int cc = (4 * t) & 127;
        #pragma unroll
        for (int c = 0; c < 4; ++c) {
            w[c][0] = *(const float4*)(of2 + (cc + c) * 8);
            w[c][1] = *(const float4*)(of2 + (cc + c) * 8 + 4);
        }
    }

    float4* out4 = (float4*)out;
    #pragma unroll
    for (int g = 0; g < 2; ++g) {
        #pragma unroll
        for (int h = 0; h < 2; ++h) {
            const int id = t + 256 * h;
            const int o = id >> 6, Bq = (id >> 3) & 7, Cr = id & 7;
            float s = 0.f;
            #pragma unroll
            for (int A = 0; A < 8; ++A)
                s = fmaf(z2[g * 512 + A * 64 + Bq * 8 + Cr], s_of0T[A * 8 + o], s);
            t1[id] = s;
        }
        __syncthreads();
        #pragma unroll
        for (int h = 0; h < 2; ++h) {
            const int id = t + 256 * h;
            const int p = id >> 6, o = (id >> 3) & 7, Cr = id & 7;
            float s = 0.f;
            #pragma unroll
            for (int B0 = 0; B0 < 8; ++B0) {
                const int Bq = (B0 + o) & 7;
                s = fmaf(t1[o * 64 + Bq * 8 + Cr], s_of1T[Bq * 8 + p], s);
            }
            t2[id] = s;
        }
        __syncthreads();
        #pragma unroll
        for (int i = 0; i < 8; ++i) {
            const int m = (t >> 5) + 8 * i;
            const int o = m >> 3, p = m & 7;
            const float wv = s_winv[g * 64 + m];
            const int base = p * 64 + o * 8;
            const float4 v0 = *(const float4*)(t2 + base);
            const float4 v1 = *(const float4*)(t2 + base + 4);
            float4 r;
            r.x = dot4(v1, w[0][1], dot4(v0, w[0][0], acc[g][i].x));
            r.y = dot4(v1, w[1][1], dot4(v0, w[1][0], acc[g][i].y));
            r.z = dot4(v1, w[2][1], dot4(v0, w[2][0], acc[g][i].z));
            r.w = dot4(v1, w[3][1], dot4(v0, w[3][0], acc[g][i].w));
            r.x *= wv; r.y *= wv; r.z *= wv; r.w *= wv;
            out4[(size_t)(blk * 2 + g) * 2048 + t + 256 * i] = r;
        }
        __syncthreads();
    }
}

extern "C" void kernel_launch(void* const* d_in, const int* in_sizes, int n_in,
                              void* d_out, int out_size, void* d_ws, size_t ws_size,
                              hipStream_t stream) {
    const float* x    = (const float*)d_in[0];
    const float* core = (const float*)d_in[1];
    const float* of0  = (const float*)d_in[2];
    const float* of1  = (const float*)d_in[3];
    const float* of2  = (const float*)d_in[4];
    const float* if0  = (const float*)d_in[5];
    const float* if1  = (const float*)d_in[6];
    const float* if2  = (const float*)d_in[7];
    const int* mask   = (const int*)d_in[8];
    float* out = (float*)d_out;

    const size_t CORE_T_BYTES = (size_t)512 * 512 * 4;            // 1 MB
    const size_t ZZ_BYTES     = (size_t)2048 * 512 * 4;           // 4 MB
    const size_t XS_BYTES     = (size_t)2048 * 8192 * 2;          // 33.5 MB bf16

    if (d_ws && ws_size >= CORE_T_BYTES + ZZ_BYTES + XS_BYTES) {
        float* coreT    = (float*)d_ws;
        float* zz_ws    = (float*)((char*)d_ws + CORE_T_BYTES);
        unsigned* xs_bf = (unsigned*)((char*)d_ws + CORE_T_BYTES + ZZ_BYTES);
        k1_inproj<<<dim3(2112), dim3(256), 0, stream>>>(
            x, core, coreT, if0, if1, if2, xs_bf, zz_ws);
        k2_core_outproj<<<dim3(512), dim3(512), 0, stream>>>(
            coreT, zz_ws, xs_bf, of0, of1, of2, mask, out);
    } else {
        noblock_fused<<<dim3(1024), dim3(256), 0, stream>>>(
            x, core, of0, of1, of2, if0, if1, if2, mask, out);
    }
}

// Round 14
// 107.612 us; speedup vs baseline: 1.4589x; 1.0390x over previous
//
#include <hip/hip_runtime.h>
#include <cstdint>
#include <cstddef>

// NOBlock: B=4, N=2048, V=1, M=64 (8x8), C=128, rank 8, GRP=4.
//
// ALGEBRA: op is linear in x; mask only sets divisor w:
//   out = winv * (Tucker(sum_j x_j) + sum_j x_j)   -> one transform per GROUP.
//
// ROUND 14: single fused main kernel (512 blocks x 512 thr, 4 groups/block).
// Same block owns its groups end-to-end -> zz lives in LDS (no ws round-trip),
// no K1->K2 grid serialization: co-resident blocks de-phase so the x HBM
// stream overlaps the coreT L2 stream. Only cross-block dep is coreT ->
// tiny transpose pre-kernel. xsum residual: packed bf16 in ws (33.5 MB).
// LDS 56.5 KB -> 2 blocks/CU (16 waves). launch_bounds(512,2) -> <=128 VGPR.

__device__ __forceinline__ float dot4(const float4 a, const float4 b, float s) {
    return fmaf(a.w, b.w, fmaf(a.z, b.z, fmaf(a.y, b.y, fmaf(a.x, b.x, s))));
}

__device__ __forceinline__ unsigned f2bf_pk(float lo, float hi) {
    // round-to-nearest-even bf16 pair packed into one uint
    unsigned ul = __float_as_uint(lo), uh = __float_as_uint(hi);
    ul += 0x7FFFu + ((ul >> 16) & 1u);
    uh += 0x7FFFu + ((uh >> 16) & 1u);
    return (ul >> 16) | (uh & 0xFFFF0000u);
}

// core[r][k] (512x512) -> cT[k>>2][r] as float4 over k&3. Coalesced stores.
__global__ void transpose_core(const float* __restrict__ core,
                               float* __restrict__ coreT) {
    const int tid = blockIdx.x * 256 + threadIdx.x;   // 0..65535
    const int r = tid & 511, k4 = tid >> 9;
    ((float4*)coreT)[(size_t)k4 * 512 + r] =
        ((const float4*)core)[(size_t)r * 128 + k4];
}

// ---- fused main kernel: 512 blocks x 512 threads, 4 groups per block ----
__launch_bounds__(512, 2)
__global__ void noblock_main(const float* __restrict__ x,
                             const float* __restrict__ coreT,
                             const float* __restrict__ of0,
                             const float* __restrict__ of1,
                             const float* __restrict__ of2,
                             const float* __restrict__ if0,
                             const float* __restrict__ if1,
                             const float* __restrict__ if2,
                             const int* __restrict__ mask,
                             unsigned* __restrict__ xsum_bf,   // ws bf16 residual
                             float* __restrict__ out)
{
    __shared__ float xs[64 * 132];      // 33.8 KB; t1/t2 alias after stage A
    __shared__ float zz[2048];          // 4 groups' z; dead after stage C -> t1d
    __shared__ float z2[2048];          // core output;  dead after D1      -> t2d
    __shared__ float s_if2T[8 * 132];   // [F][e], padded
    __shared__ float s_if0[64], s_if1[64];
    __shared__ float s_of0T[64], s_of1T[64];   // [A][o], [B][p]
    __shared__ float s_winv[256];       // [g][m]
    float* t1 = xs;                     // aliases (xs dead after stage-A reads)
    float* t2 = xs + 512;
    float* t1d = zz;
    float* t2d = z2;

    const int t = threadIdx.x;          // 0..511
    const size_t g0 = (size_t)blockIdx.x * 4;

    // ---- staging: factors (if2 transposed), winv ----
    for (int i = t; i < 1024; i += 512) {
        const int e = i & 127, F = i >> 7;
        s_if2T[F * 132 + e] = if2[e * 8 + F];
    }
    if (t < 64) {
        s_if0[t] = if0[t];
        s_if1[t] = if1[t];
        s_of0T[t] = of0[(t & 7) * 8 + (t >> 3)];
        s_of1T[t] = of1[(t & 7) * 8 + (t >> 3)];
    }
    if (t < 256) {
        const int g = t >> 6, m = t & 63;
        const int* mp = mask + (g0 + g) * 4 * 64 + m;
        int cnt = 0;
        #pragma unroll
        for (int j = 0; j < 4; ++j) cnt += (mp[j * 64] == 0) ? 1 : 0;
        s_winv[t] = cnt ? 1.0f / (float)cnt : 0.0f;
    }
    // first __syncthreads below (inside group 0 phase A) covers staging

    // ---- phase A: per group, xsum + in-projection -> zz (LDS) ----
    #pragma unroll 1
    for (int g = 0; g < 4; ++g) {
        const float4* xg4 = (const float4*)x + (g0 + g) * 8192;  // 4 tokens
        // all 16 loads issued up-front for MLP
        float4 v[4][4];
        #pragma unroll
        for (int j = 0; j < 4; ++j)
            #pragma unroll
            for (int i = 0; i < 4; ++i)
                v[j][i] = xg4[(size_t)j * 2048 + t + 512 * i];
        float4 acc[4];
        #pragma unroll
        for (int i = 0; i < 4; ++i) {
            acc[i].x = (v[0][i].x + v[1][i].x) + (v[2][i].x + v[3][i].x);
            acc[i].y = (v[0][i].y + v[1][i].y) + (v[2][i].y + v[3][i].y);
            acc[i].z = (v[0][i].z + v[1][i].z) + (v[2][i].z + v[3][i].z);
            acc[i].w = (v[0][i].w + v[1][i].w) + (v[2][i].w + v[3][i].w);
        }
        // bf16 residual -> ws (coalesced uint2)
        uint2* xo = (uint2*)xsum_bf + (g0 + g) * 2048;
        #pragma unroll
        for (int i = 0; i < 4; ++i) {
            uint2 pk;
            pk.x = f2bf_pk(acc[i].x, acc[i].y);
            pk.y = f2bf_pk(acc[i].z, acc[i].w);
            xo[t + 512 * i] = pk;
        }
        // padded LDS tile
        #pragma unroll
        for (int i = 0; i < 4; ++i) {
            const int f4i = t + 512 * i;
            *(float4*)&xs[(f4i >> 5) * 132 + (f4i & 31) * 4] = acc[i];
        }
        __syncthreads();

        // stage A: one output/thread: r = sum_e xs[m][e] * if2T[F][e]
        float r0;
        {
            const int m = t >> 3, F = t & 7;
            const float4* xr = (const float4*)(xs + m * 132);
            const float4* wr = (const float4*)(s_if2T + F * 132);
            float s0 = 0.f, s1 = 0.f;
            #pragma unroll
            for (int e4 = 0; e4 < 32; e4 += 2) {
                s0 = dot4(xr[e4],     wr[e4],     s0);
                s1 = dot4(xr[e4 + 1], wr[e4 + 1], s1);
            }
            r0 = s0 + s1;
        }
        __syncthreads();   // all stage-A reads of xs complete
        t1[t] = r0;
        __syncthreads();   // t1 ready

        // B1: t2[E*64+a*8+F] = sum_d t1[a*64+d*8+F] * if1[d][E]
        {
            const int E = t >> 6, a = (t >> 3) & 7, F = t & 7;
            float s = 0.f;
            #pragma unroll
            for (int d0 = 0; d0 < 8; ++d0) {
                const int d = (d0 + a) & 7;           // stagger: 2-way banks
                s = fmaf(t1[a * 64 + d * 8 + F], s_if1[d * 8 + E], s);
            }
            t2[t] = s;
        }
        __syncthreads();   // t2 ready

        // B2: zz[g*512 + D*64+E*8+F] = sum_a t2[E*64+a*8+F] * if0[a][D]
        {
            const int D = t >> 6, E = (t >> 3) & 7, F = t & 7;
            float s = 0.f;
            #pragma unroll
            for (int a0 = 0; a0 < 8; ++a0) {
                const int a = (a0 + E) & 7;           // stagger: 2-way banks
                s = fmaf(t2[E * 64 + a * 8 + F], s_if0[a * 8 + D], s);
            }
            zz[g * 512 + t] = s;
        }
        __syncthreads();   // zz[g] ready; xs/t1/t2 reusable next group
    }

    // ---- stage C: z2[g][r] = sum_k coreT[k][r] * zz[g][k]; 1 row/thread,
    // coalesced L2 stream, 8 independent FMA chains (4 groups x even/odd k4)
    {
        const float4* cT = (const float4*)coreT;
        const float4* z4 = (const float4*)zz;
        float a0[4] = {0, 0, 0, 0}, a1[4] = {0, 0, 0, 0};
        for (int k4 = 0; k4 < 128; k4 += 2) {
            const float4 c0 = cT[(size_t)k4 * 512 + t];
            const float4 c1 = cT[(size_t)(k4 + 1) * 512 + t];
            #pragma unroll
            for (int g = 0; g < 4; ++g) {
                a0[g] = dot4(c0, z4[g * 128 + k4],     a0[g]);   // LDS broadcast
                a1[g] = dot4(c1, z4[g * 128 + k4 + 1], a1[g]);
            }
        }
        #pragma unroll
        for (int g = 0; g < 4; ++g) z2[g * 512 + t] = a0[g] + a1[g];
    }
    __syncthreads();   // zz dead from here

    // ---- D1 (batched): t1d[g][o*64+Bq*8+Cr] = sum_A z2[g][..] * of0T[A][o] ----
    #pragma unroll
    for (int h = 0; h < 4; ++h) {
        const int id2 = t + 512 * h;
        const int g = id2 >> 9, rem = id2 & 511;
        const int o = rem >> 6, Bq = (rem >> 3) & 7, Cr = rem & 7;
        float s = 0.f;
        #pragma unroll
        for (int A = 0; A < 8; ++A)
            s = fmaf(z2[g * 512 + A * 64 + Bq * 8 + Cr], s_of0T[A * 8 + o], s);
        t1d[id2] = s;
    }
    __syncthreads();   // z2 dead from here

    // ---- D2 (batched): t2d[g][p*64+o*8+Cr] = sum_B t1d[g][..] * of1T[B][p] ----
    #pragma unroll
    for (int h = 0; h < 4; ++h) {
        const int id2 = t + 512 * h;
        const int g = id2 >> 9, rem = id2 & 511;
        const int p = rem >> 6, o = (rem >> 3) & 7, Cr = rem & 7;
        float s = 0.f;
        #pragma unroll
        for (int B0 = 0; B0 < 8; ++B0) {
            const int Bq = (B0 + o) & 7;              // stagger: 2-way banks
            s = fmaf(t1d[g * 512 + o * 64 + Bq * 8 + Cr], s_of1T[Bq * 8 + p], s);
        }
        t2d[id2] = s;
    }
    __syncthreads();

    // ---- D3: h = v.of2 + bf16(xsum), *winv, write d_out (write-once) ----
    float4 w[4][2];
    {
        const int cc = (4 * t) & 127;
        #pragma unroll
        for (int c = 0; c < 4; ++c) {
            w[c][0] = *(const float4*)(of2 + (cc + c) * 8);
            w[c][1] = *(const float4*)(of2 + (cc + c) * 8 + 4);
        }
    }
    float4* out4 = (float4*)out;
    #pragma unroll
    for (int g = 0; g < 4; ++g) {
        const size_t obase = (g0 + g) * 2048;
        const uint2* xb = (const uint2*)xsum_bf + obase;
        uint2 xp[4];
        #pragma unroll
        for (int i = 0; i < 4; ++i) xp[i] = xb[t + 512 * i];
        #pragma unroll
        for (int i = 0; i < 4; ++i) {
            const int m = (t >> 5) + 16 * i;
            const int o = m >> 3, p = m & 7;
            const float wv = s_winv[g * 64 + m];
            const int base = g * 512 + p * 64 + o * 8;
            const float4 v0 = *(const float4*)(t2d + base);   // broadcast
            const float4 v1 = *(const float4*)(t2d + base + 4);
            const float rx = __uint_as_float(xp[i].x << 16);
            const float ry = __uint_as_float(xp[i].x & 0xFFFF0000u);
            const float rz = __uint_as_float(xp[i].y << 16);
            const float rw = __uint_as_float(xp[i].y & 0xFFFF0000u);
            float4 r;
            r.x = dot4(v1, w[0][1], dot4(v0, w[0][0], rx));
            r.y = dot4(v1, w[1][1], dot4(v0, w[1][0], ry));
            r.z = dot4(v1, w[2][1], dot4(v0, w[2][0], rz));
            r.w = dot4(v1, w[3][1], dot4(v0, w[3][0], rw));
            r.x *= wv; r.y *= wv; r.z *= wv; r.w *= wv;
            out4[obase + t + 512 * i] = r;
        }
    }
}

// ================= fallback (no ws): single fused kernel, strided core ======
__launch_bounds__(256, 3)
__global__ void noblock_fused(const float* __restrict__ x,
                              const float* __restrict__ core,
                              const float* __restrict__ of0,
                              const float* __restrict__ of1,
                              const float* __restrict__ of2,
                              const float* __restrict__ if0,
                              const float* __restrict__ if1,
                              const float* __restrict__ if2,
                              const int* __restrict__ mask,
                              float* __restrict__ out)
{
    __shared__ float xs[64 * 132];
    __shared__ float t1[512];
    __shared__ float t2[512];
    __shared__ float zz[2 * 512];
    __shared__ float z2[2 * 512];
    __shared__ float s_if2T[8 * 132];
    __shared__ float s_if0[64], s_if1[64];
    __shared__ float s_of0T[64], s_of1T[64];
    __shared__ float s_winv[128];

    const int t = threadIdx.x;
    const int blk = blockIdx.x;

    for (int i = t; i < 1024; i += 256) {
        const int e = i & 127, F = i >> 7;
        s_if2T[F * 132 + e] = if2[e * 8 + F];
    }
    if (t < 64) {
        s_if0[t] = if0[t];
        s_if1[t] = if1[t];
        s_of0T[t] = of0[(t & 7) * 8 + (t >> 3)];
        s_of1T[t] = of1[(t & 7) * 8 + (t >> 3)];
    }
    if (t < 128) {
        const int g = t >> 6, mm = t & 63;
        const int* mp = mask + ((size_t)(blk * 2 + g) * 4) * 64 + mm;
        int cnt = 0;
        #pragma unroll
        for (int j = 0; j < 4; ++j) cnt += (mp[j * 64] == 0) ? 1 : 0;
        s_winv[t] = cnt ? 1.0f / (float)cnt : 0.0f;
    }

    float4 acc[2][8];
    const float4* xg4 = (const float4*)(x + (size_t)blk * 8 * 8192);
    #pragma unroll
    for (int g = 0; g < 2; ++g)
        #pragma unroll
        for (int i = 0; i < 8; ++i)
            acc[g][i] = xg4[(size_t)(g * 4) * 2048 + t + 256 * i];
    #pragma unroll
    for (int j = 1; j < 4; ++j) {
        #pragma unroll
        for (int g = 0; g < 2; ++g) {
            float4 v[8];
            #pragma unroll
            for (int i = 0; i < 8; ++i)
                v[i] = xg4[(size_t)(g * 4 + j) * 2048 + t + 256 * i];
            #pragma unroll
            for (int i = 0; i < 8; ++i) {
                acc[g][i].x += v[i].x; acc[g][i].y += v[i].y;
                acc[g][i].z += v[i].z; acc[g][i].w += v[i].w;
            }
        }
    }

    #pragma unroll
    for (int g = 0; g < 2; ++g) {
        #pragma unroll
        for (int i = 0; i < 8; ++i) {
            const int f4i = t + 256 * i;
            *(float4*)&xs[(f4i >> 5) * 132 + (f4i & 31) * 4] = acc[g][i];
        }
        __syncthreads();
        #pragma unroll
        for (int h = 0; h < 2; ++h) {
            const int id = t + 256 * h;
            const int m = id >> 3, F = id & 7;
            const float4* xr = (const float4*)(xs + m * 132);
            const float4* wr = (const float4*)(s_if2T + F * 132);
            float s0 = 0.f, s1 = 0.f;
            #pragma unroll
            for (int e4 = 0; e4 < 32; e4 += 2) {
                s0 = dot4(xr[e4],     wr[e4],     s0);
                s1 = dot4(xr[e4 + 1], wr[e4 + 1], s1);
            }
            t1[id] = s0 + s1;
        }
        __syncthreads();
        #pragma unroll
        for (int h = 0; h < 2; ++h) {
            const int id = t + 256 * h;
            const int E = id >> 6, a = (id >> 3) & 7, F = id & 7;
            float s = 0.f;
            #pragma unroll
            for (int d0 = 0; d0 < 8; ++d0) {
                const int d = (d0 + a) & 7;
                s = fmaf(t1[a * 64 + d * 8 + F], s_if1[d * 8 + E], s);
            }
            t2[id] = s;
        }
        __syncthreads();
        #pragma unroll
        for (int h = 0; h < 2; ++h) {
            const int id = t + 256 * h;
            const int D = id >> 6, E = (id >> 3) & 7, F = id & 7;
            float s = 0.f;
            #pragma unroll
            for (int a0 = 0; a0 < 8; ++a0) {
                const int a = (a0 + E) & 7;
                s = fmaf(t2[E * 64 + a * 8 + F], s_if0[a * 8 + D], s);
            }
            zz[g * 512 + id] = s;
        }
        __syncthreads();
    }

    {
        const float4* cr0 = (const float4*)(core + (size_t)t * 512);
        const float4* cr1 = (const float4*)(core + (size_t)(t + 256) * 512);
        const float4* z4 = (const float4*)zz;
        float a0[2] = {0.f, 0.f}, a1[2] = {0.f, 0.f};
        for (int kk = 0; kk < 128; ++kk) {
            const float4 c0 = cr0[kk], c1 = cr1[kk];
            #pragma unroll
            for (int g = 0; g < 2; ++g) {
                const float4 zv = z4[g * 128 + kk];
                a0[g] = dot4(c0, zv, a0[g]);
                a1[g] = dot4(c1, zv, a1[g]);
            }
        }
        #pragma unroll
        for (int g = 0; g < 2; ++g) {
            z2[g * 512 + t]       = a0[g];
            z2[g * 512 + t + 256] = a1[g];
        }
    }
    __syncthreads();

    float4 w[4][2];
    {
        const int cc = (4 * t) & 127;
        #pragma unroll
        for (int c = 0; c < 4; ++c) {
            w[c][0] = *(const float4*)(of2 + (cc + c) * 8);
            w[c][1] = *(const float4*)(of2 + (cc + c) * 8 + 4);
        }
    }

    float4* out4 = (float4*)out;
    #pragma unroll
    for (int g = 0; g < 2; ++g) {
        #pragma unroll
        for (int h = 0; h < 2; ++h) {
            const int id = t + 256 * h;
            const int o = id >> 6, Bq = (id >> 3) & 7, Cr = id & 7;
            float s = 0.f;
            #pragma unroll
            for (int A = 0; A < 8; ++A)
                s = fmaf(z2[g * 512 + A * 64 + Bq * 8 + Cr], s_of0T[A * 8 + o], s);
            t1[id] = s;
        }
        __syncthreads();
        #pragma unroll
        for (int h = 0; h < 2; ++h) {
            const int id = t + 256 * h;
            const int p = id >> 6, o = (id >> 3) & 7, Cr = id & 7;
            float s = 0.f;
            #pragma unroll
            for (int B0 = 0; B0 < 8; ++B0) {
                const int Bq = (B0 + o) & 7;
                s = fmaf(t1[o * 64 + Bq * 8 + Cr], s_of1T[Bq * 8 + p], s);
            }
            t2[id] = s;
        }
        __syncthreads();
        #pragma unroll
        for (int i = 0; i < 8; ++i) {
            const int m = (t >> 5) + 8 * i;
            const int o = m >> 3, p = m & 7;
            const float wv = s_winv[g * 64 + m];
            const int base = p * 64 + o * 8;
            const float4 v0 = *(const float4*)(t2 + base);
            const float4 v1 = *(const float4*)(t2 + base + 4);
            float4 r;
            r.x = dot4(v1, w[0][1], dot4(v0, w[0][0], acc[g][i].x));
            r.y = dot4(v1, w[1][1], dot4(v0, w[1][0], acc[g][i].y));
            r.z = dot4(v1, w[2][1], dot4(v0, w[2][0], acc[g][i].z));
            r.w = dot4(v1, w[3][1], dot4(v0, w[3][0], acc[g][i].w));
            r.x *= wv; r.y *= wv; r.z *= wv; r.w *= wv;
            out4[(size_t)(blk * 2 + g) * 2048 + t + 256 * i] = r;
        }
        __syncthreads();
    }
}

extern "C" void kernel_launch(void* const* d_in, const int* in_sizes, int n_in,
                              void* d_out, int out_size, void* d_ws, size_t ws_size,
                              hipStream_t stream) {
    const float* x    = (const float*)d_in[0];
    const float* core = (const float*)d_in[1];
    const float* of0  = (const float*)d_in[2];
    const float* of1  = (const float*)d_in[3];
    const float* of2  = (const float*)d_in[4];
    const float* if0  = (const float*)d_in[5];
    const float* if1  = (const float*)d_in[6];
    const float* if2  = (const float*)d_in[7];
    const int* mask   = (const int*)d_in[8];
    float* out = (float*)d_out;

    const size_t CORE_T_BYTES = (size_t)512 * 512 * 4;            // 1 MB
    const size_t XS_BYTES     = (size_t)2048 * 8192 * 2;          // 33.5 MB bf16

    if (d_ws && ws_size >= CORE_T_BYTES + XS_BYTES) {
        float* coreT    = (float*)d_ws;
        unsigned* xs_bf = (unsigned*)((char*)d_ws + CORE_T_BYTES);
        transpose_core<<<dim3(256), dim3(256), 0, stream>>>(core, coreT);
        noblock_main<<<dim3(512), dim3(512), 0, stream>>>(
            x, coreT, of0, of1, of2, if0, if1, if2, mask, xs_bf, out);
    } else {
        noblock_fused<<<dim3(1024), dim3(256), 0, stream>>>(
            x, core, of0, of1, of2, if0, if1, if2, mask, out);
    }
}